// Round 10
// baseline (588.317 us; speedup 1.0000x reference)
//
#include <hip/hip_runtime.h>
#include <cstdint>
#include <cstddef>

#define F_IN 128
#define HC12 256   // HEADS*HID for layers 1/2
#define KG3 1280   // hG row stride (u16): [h2 (256) | G (4x256)]
#define NCLS 121

typedef unsigned short u16;
typedef unsigned int u32;
typedef __attribute__((ext_vector_type(8))) short short8;
typedef __attribute__((ext_vector_type(8))) __fp16 half8;
typedef __attribute__((ext_vector_type(4))) float float4v;

static __device__ __forceinline__ float lrelu(float x) { return x > 0.f ? x : 0.2f * x; }

static __device__ __forceinline__ u16 f2h(float f) {
    union { __fp16 h; u16 u; } v; v.h = (__fp16)f; return v.u;
}
static __device__ __forceinline__ float h2f(u16 u) {
    union { u16 u; __fp16 h; } v; v.u = u; return (float)v.h;
}

static __device__ __forceinline__ void gload16(const u16* g, u16* l) {
    __builtin_amdgcn_global_load_lds((const __attribute__((address_space(1))) void*)g,
                                     (__attribute__((address_space(3))) void*)l,
                                     16, 0, 0);
}

// ---------------- CSR build ----------------
__global__ void hist_kernel(const int* __restrict__ dst, int* __restrict__ deg, int E) {
    int e = blockIdx.x * 256 + threadIdx.x;
    if (e < E) atomicAdd(&deg[dst[e]], 1);
}

__global__ __launch_bounds__(256) void scan_part(const int* __restrict__ deg,
                                                 int* __restrict__ part, int N) {
    int b = blockIdx.x;
    int i0 = b * 1024 + threadIdx.x * 4;
    int t = 0;
    if (i0     < N) t += deg[i0];
    if (i0 + 1 < N) t += deg[i0 + 1];
    if (i0 + 2 < N) t += deg[i0 + 2];
    if (i0 + 3 < N) t += deg[i0 + 3];
#pragma unroll
    for (int o = 1; o < 64; o <<= 1) t += __shfl_xor(t, o, 64);
    __shared__ int sw[4];
    int w = threadIdx.x >> 6, lane = threadIdx.x & 63;
    if (!lane) sw[w] = t;
    __syncthreads();
    if (threadIdx.x == 0) part[b] = sw[0] + sw[1] + sw[2] + sw[3];
}

__global__ void scan_mid(int* __restrict__ part, int nb) {
    int lane = threadIdx.x;   // 64 threads
    __shared__ int carry_s;
    if (lane == 0) carry_s = 0;
    __syncthreads();
    for (int base = 0; base < nb; base += 64) {
        int i = base + lane;
        int v = (i < nb) ? part[i] : 0;
        int sc = v;
#pragma unroll
        for (int o = 1; o < 64; o <<= 1) {
            int u = __shfl_up(sc, o, 64);
            if (lane >= o) sc += u;
        }
        int carry = carry_s;
        if (i < nb) part[i] = carry + sc - v;   // exclusive prefix
        __syncthreads();
        if (lane == 63) carry_s = carry + sc;
        __syncthreads();
    }
}

__global__ __launch_bounds__(256) void scan_final(const int* __restrict__ deg,
                                                  const int* __restrict__ part,
                                                  int* __restrict__ rowp, int N) {
    int b = blockIdx.x;
    int tid = threadIdx.x;
    int w = tid >> 6, lane = tid & 63;
    int i0 = b * 1024 + tid * 4;
    int v0 = (i0     < N) ? deg[i0]     : 0;
    int v1 = (i0 + 1 < N) ? deg[i0 + 1] : 0;
    int v2 = (i0 + 2 < N) ? deg[i0 + 2] : 0;
    int v3 = (i0 + 3 < N) ? deg[i0 + 3] : 0;
    int t = v0 + v1 + v2 + v3;
    int sc = t;
#pragma unroll
    for (int o = 1; o < 64; o <<= 1) {
        int u = __shfl_up(sc, o, 64);
        if (lane >= o) sc += u;
    }
    __shared__ int sw2[4];
    if (lane == 63) sw2[w] = sc;
    __syncthreads();
    int cw = 0;
    for (int x = 0; x < w; x++) cw += sw2[x];
    int tb = part[b] + cw + sc - t;
    if (i0     < N) rowp[i0 + 1] = tb + v0;
    if (i0 + 1 < N) rowp[i0 + 2] = tb + v0 + v1;
    if (i0 + 2 < N) rowp[i0 + 3] = tb + v0 + v1 + v2;
    if (i0 + 3 < N) rowp[i0 + 4] = tb + t;
    if (b == 0 && tid == 0) rowp[0] = 0;
}

__global__ void scatter_kernel(const int* __restrict__ src, const int* __restrict__ dst,
                               const int* __restrict__ rowp, int* __restrict__ cur,
                               int* __restrict__ col, int E) {
    int e = blockIdx.x * 256 + threadIdx.x;
    if (e < E) {
        int d = dst[e];
        int pos = rowp[d] + atomicAdd(&cur[d], 1);
        col[pos] = src[e];
    }
}

// ---------------- fused weight transpose to f16 ----------------
// C3 = combined [121 cols][1280 K] weight: rows 0-255 = lin3W, rows 256+h*256+k = 0.25*W3[k, h*121+c]
__global__ void cvtT_all_kernel(const float* W1, const float* l1W, const float* W2,
                                const float* W3, const float* l3W,
                                u16* C1, u16* C2, u16* C3) {
    int i = blockIdx.x * 256 + threadIdx.x;
    if (i >= 285952) return;
    if (i >= 131072) {
        int j = i - 131072;          // 0 .. 154879 = 121*1280
        int c = j % NCLS, k = j / NCLS;
        float v;
        if (k < 256) v = l3W[(size_t)k * NCLS + c];
        else {
            int kp = k - 256;
            v = 0.25f * W3[(size_t)(kp & 255) * 484 + (kp >> 8) * NCLS + c];
        }
        C3[(size_t)c * KG3 + k] = f2h(v);
        return;
    }
    const float* B; u16* o; int K, N;
    if (i < 32768)      { B = W1;  o = C1;             K = 128; N = 256; }
    else if (i < 65536) { B = l1W; o = C1 + 256 * 128; K = 128; N = 256; i -= 32768; }
    else                { B = W2;  o = C2;             K = 256; N = 256; i -= 65536; }
    int n = i % N, k = i / N;
    o[(size_t)n * K + k] = f2h(B[(size_t)k * N + n]);
}

// ---------------- projected layer-3 attention vectors: p[h] = W3[:,h-block] @ a3 ----------------
__global__ __launch_bounds__(256) void prep3_kernel(const float* __restrict__ W3,
                                                    const float* __restrict__ a3s,
                                                    const float* __restrict__ a3d,
                                                    float* __restrict__ ps,
                                                    float* __restrict__ pd) {
    int idx = blockIdx.x * 256 + threadIdx.x;   // 2048 items: t(2) x h(4) x k(256)
    if (idx >= 2048) return;
    int t = idx >> 10, h = (idx >> 8) & 3, k = idx & 255;
    const float* a = t ? a3d : a3s;
    const float* wrow = W3 + (size_t)k * 484 + h * NCLS;
    const float* arow = a + h * NCLS;
    float s = 0.f;
    for (int c = 0; c < NCLS; c++) s += wrow[c] * arow[c];
    (t ? pd : ps)[h * 256 + k] = s;
}

// ---------------- bias prefill for split-K atomic accumulation ----------------
__global__ __launch_bounds__(256) void fill_bias_kernel(float* __restrict__ out,
                                                        const float* __restrict__ b3,
                                                        int total) {
    int i = blockIdx.x * 256 + threadIdx.x;
    if (i < total) out[i] = b3[i % NCLS];
}

// ---------------- x fp32 -> f16 ----------------
__global__ __launch_bounds__(256) void xcvt_kernel(const float* __restrict__ x,
                                                   u16* __restrict__ o, int total8) {
    int i = blockIdx.x * 256 + threadIdx.x;
    if (i >= total8) return;
    const float4* p = (const float4*)(x + (size_t)i * 8);
    float4 a = p[0], b = p[1];
    union { u16 u[8]; short8 v; } r;
    r.u[0] = f2h(a.x); r.u[1] = f2h(a.y); r.u[2] = f2h(a.z); r.u[3] = f2h(a.w);
    r.u[4] = f2h(b.x); r.u[5] = f2h(b.y); r.u[6] = f2h(b.z); r.u[7] = f2h(b.w);
    *(short8*)(o + (size_t)i * 8) = r.v;
}

// ---------------- f16 MFMA GEMM, 128x128 tile, global_load_lds staging ----------------
// nkc>1: split-K mode — grid = nkc*ny blocks, single column-block, atomicAdd epilogue.
#define BM 128
#define BN 128
#define BK 32

__global__ __launch_bounds__(256, 3) void gemm_f16(const u16* __restrict__ A16,
                                                   const u16* __restrict__ BT,
                                                   int M, int K, int Ntot,
                                                   int nx, int ny,
                                                   int Nb, u16* __restrict__ Cb, int strideB,
                                                   u16* __restrict__ Cf16,
                                                   float* __restrict__ Cf32,
                                                   const float* __restrict__ biasf, int strideF,
                                                   int nkc, int accum) {
    __shared__ __align__(16) u16 sA[BM * BK];
    __shared__ __align__(16) u16 sB[BN * BK];
    int tid = threadIdx.x;
    int wave = tid >> 6, lane = tid & 63;
    int wr = wave >> 1, wc = wave & 1;

    int bid = blockIdx.x;
    int rb, cb;
    int kc0 = 0, kcN = K;
    if (nkc > 1) {
        // split-K: bid = chunk*ny + rb, single column-block
        int chunk = bid / ny;
        rb = bid - chunk * ny;
        cb = 0;
        int Kc = K / nkc;
        kc0 = chunk * Kc;
        kcN = kc0 + Kc;
    } else {
        // XCD-aware block swizzle
        int G = nx * 8;
        int g = bid / G;
        int rem = ny - g * 8;
        if (rem >= 8) {
            int r = bid - g * G;
            rb = g * 8 + (r & 7);
            cb = r >> 3;
        } else {
            int t = bid - g * G;
            rb = g * 8 + t % rem;
            cb = t / rem;
        }
    }
    int m0 = rb * BM, n0 = cb * BN;

    int fm = lane & 15;
    int q = lane >> 4;

    int srow = lane >> 2;
    int sch = (lane & 3) * 8;
    u16* lA0 = &sA[(wave * 32) * BK];
    u16* lA1 = &sA[(wave * 32 + 16) * BK];
    u16* lB0 = &sB[(wave * 32) * BK];
    u16* lB1 = &sB[(wave * 32 + 16) * BK];
    int ar0 = min(m0 + wave * 32 + srow, M - 1);
    int ar1 = min(m0 + wave * 32 + 16 + srow, M - 1);
    int br0 = min(n0 + wave * 32 + srow, Ntot - 1);
    int br1 = min(n0 + wave * 32 + 16 + srow, Ntot - 1);

    float4v acc[4][4];
#pragma unroll
    for (int i = 0; i < 4; i++)
#pragma unroll
        for (int j = 0; j < 4; j++) acc[i][j] = (float4v){0.f, 0.f, 0.f, 0.f};

    for (int kc = kc0; kc < kcN; kc += BK) {
        gload16(&A16[(size_t)ar0 * K + kc + sch], lA0);
        gload16(&A16[(size_t)ar1 * K + kc + sch], lA1);
        gload16(&BT[(size_t)br0 * K + kc + sch], lB0);
        gload16(&BT[(size_t)br1 * K + kc + sch], lB1);
        __syncthreads();

        half8 ah[4];
#pragma unroll
        for (int mi = 0; mi < 4; mi++)
            ah[mi] = *(const half8*)&sA[(wr * 64 + mi * 16 + fm) * BK + q * 8];
#pragma unroll
        for (int ni = 0; ni < 4; ni++) {
            half8 bh = *(const half8*)&sB[(wc * 64 + ni * 16 + fm) * BK + q * 8];
#pragma unroll
            for (int mi = 0; mi < 4; mi++)
                acc[mi][ni] = __builtin_amdgcn_mfma_f32_16x16x32_f16(ah[mi], bh, acc[mi][ni], 0, 0, 0);
        }
        __syncthreads();
    }

#pragma unroll
    for (int mi = 0; mi < 4; mi++) {
#pragma unroll
        for (int ni = 0; ni < 4; ni++) {
            int colg = n0 + wc * 64 + ni * 16 + fm;
            if (colg >= Ntot) continue;
#pragma unroll
            for (int r = 0; r < 4; r++) {
                int rowg = m0 + wr * 64 + mi * 16 + q * 4 + r;
                if (rowg >= M) continue;
                float v = acc[mi][ni][r];
                if (accum) {
                    atomicAdd(&Cf32[(size_t)rowg * strideF + (colg - Nb)], v);
                } else if (colg < Nb) {
                    Cb[(size_t)rowg * strideB + colg] = f2h(v);
                } else {
                    int cf = colg - Nb;
                    float vb = v + biasf[cf];
                    if (Cf32) Cf32[(size_t)rowg * strideF + cf] = vb;
                    else      Cf16[(size_t)rowg * strideF + cf] = f2h(vb);
                }
            }
        }
    }
}

// ---------------- wave-per-node attention coefficients, C=64 (layers 1/2) ----------------
__global__ __launch_bounds__(256) void alpha_wave_256(const u16* __restrict__ xh,
                                                      const float* __restrict__ a_s,
                                                      const float* __restrict__ a_d,
                                                      float* __restrict__ as_o,
                                                      float* __restrict__ ad_o, int N) {
    int lane = threadIdx.x & 63;
    int n = blockIdx.x * 4 + (threadIdx.x >> 6);
    if (n >= N) return;
    int c = lane * 4;
    uint2 v = *(const uint2*)&xh[(size_t)n * HC12 + c];
    float4 s4 = *(const float4*)&a_s[c];
    float4 d4 = *(const float4*)&a_d[c];
    float x0 = h2f((u16)(v.x & 0xffff)), x1 = h2f((u16)(v.x >> 16));
    float x2 = h2f((u16)(v.y & 0xffff)), x3 = h2f((u16)(v.y >> 16));
    float ss = x0 * s4.x + x1 * s4.y + x2 * s4.z + x3 * s4.w;
    float sd = x0 * d4.x + x1 * d4.y + x2 * d4.z + x3 * d4.w;
#pragma unroll
    for (int o = 1; o < 16; o <<= 1) {
        ss += __shfl_xor(ss, o, 64);
        sd += __shfl_xor(sd, o, 64);
    }
    if ((lane & 15) == 0) {
        as_o[n * 4 + (lane >> 4)] = ss;
        ad_o[n * 4 + (lane >> 4)] = sd;
    }
}

// ---------------- layer-3 attention coefficients from h2 via projected vectors ----------------
__global__ __launch_bounds__(256) void alpha3_dot(const u16* __restrict__ hG,
                                                  const float* __restrict__ ps,
                                                  const float* __restrict__ pd,
                                                  float* __restrict__ as_o,
                                                  float* __restrict__ ad_o, int N) {
    int l = threadIdx.x & 63;
    int n = blockIdx.x * 4 + (threadIdx.x >> 6);
    if (n >= N) return;
    int h = l >> 4, li = l & 15;
    int c = li * 16;
    const u16* row = hG + (size_t)n * KG3 + c;
    uint4 v0 = *(const uint4*)&row[0];
    uint4 v1 = *(const uint4*)&row[8];
    u32 ww[8] = {v0.x, v0.y, v0.z, v0.w, v1.x, v1.y, v1.z, v1.w};
    const float* psr = ps + h * 256 + c;
    const float* pdr = pd + h * 256 + c;
    float ss = 0.f, sd = 0.f;
#pragma unroll
    for (int j = 0; j < 8; j++) {
        float lo = h2f((u16)(ww[j] & 0xffff));
        float hi = h2f((u16)(ww[j] >> 16));
        ss += lo * psr[2 * j] + hi * psr[2 * j + 1];
        sd += lo * pdr[2 * j] + hi * pdr[2 * j + 1];
    }
#pragma unroll
    for (int o = 1; o < 16; o <<= 1) {
        ss += __shfl_xor(ss, o, 64);
        sd += __shfl_xor(sd, o, 64);
    }
    if (li == 0) {
        as_o[n * 4 + h] = ss;
        ad_o[n * 4 + h] = sd;
    }
}

// ---------------- FUSED online-softmax aggregate, HC=256 (layers 1/2) ----------------
__global__ __launch_bounds__(256) void agg_fused_256(const u16* __restrict__ xh,
                                                     const int* __restrict__ rowp,
                                                     const int* __restrict__ col,
                                                     const float* __restrict__ asrc,
                                                     const float* __restrict__ adst,
                                                     const float* __restrict__ bias,
                                                     const u16* __restrict__ res16,
                                                     u16* __restrict__ out16, int ostride,
                                                     int N) {
    int l = threadIdx.x & 63;
    int n = blockIdx.x * 4 + (threadIdx.x >> 6);
    if (n >= N) return;
    int r0 = rowp[n], r1 = rowp[n + 1];
    int s_slot = l >> 5, li = l & 31;
    int c = li * 8;
    int h = li >> 3;            // own head (gather role)
    int hs = l & 3;             // stats head
    int e_st = l >> 2;          // stats edge slot 0..15
    float ad = adst[n * 4 + hs];
    float m = -3.4e38f, ssum = 0.f;
    float acc[8] = {0.f, 0.f, 0.f, 0.f, 0.f, 0.f, 0.f, 0.f};
    for (int kb = r0; kb < r1; kb += 16) {
        int cn = min(16, r1 - kb);
        int cidx = col[kb + (l & 15)];
        // ---- stats phase (online softmax) ----
        int esc = __shfl(cidx, e_st, 64);
        bool ev = e_st < cn;
        float lg = ev ? lrelu(asrc[esc * 4 + hs] + ad) : -3.4e38f;
        float cm = lg;
#pragma unroll
        for (int o = 4; o < 64; o <<= 1) cm = fmaxf(cm, __shfl_xor(cm, o, 64));
        float mn = fmaxf(m, cm);
        float es = __expf(m - mn);
        float atil = ev ? __expf(lg - mn) : 0.f;
        float cs = atil;
#pragma unroll
        for (int o = 4; o < 64; o <<= 1) cs += __shfl_xor(cs, o, 64);
        ssum = ssum * es + cs;
        m = mn;
        float eso = __shfl(es, (l & 60) | h, 64);   // rescale for own head
#pragma unroll
        for (int j = 0; j < 8; j++) acc[j] *= eso;
        // ---- gather phase ----
        int npair = (cn + 1) >> 1;
#pragma unroll 4
        for (int k = 0; k < npair; k++) {
            int e = 2 * k + s_slot;
            int em = e < cn ? e : cn - 1;
            int src = __shfl(cidx, em, 64);
            float al = __shfl(atil, em * 4 + h, 64);
            if (e >= cn) al = 0.f;
            uint4 v = *(const uint4*)&xh[(size_t)src * HC12 + c];
            acc[0] += al * h2f((u16)(v.x & 0xffff));
            acc[1] += al * h2f((u16)(v.x >> 16));
            acc[2] += al * h2f((u16)(v.y & 0xffff));
            acc[3] += al * h2f((u16)(v.y >> 16));
            acc[4] += al * h2f((u16)(v.z & 0xffff));
            acc[5] += al * h2f((u16)(v.z >> 16));
            acc[6] += al * h2f((u16)(v.w & 0xffff));
            acc[7] += al * h2f((u16)(v.w >> 16));
        }
    }
    float sso = __shfl(ssum, (l & 60) | h, 64);
    float inv = 1.f / (sso + 1e-16f);
#pragma unroll
    for (int j = 0; j < 8; j++) acc[j] += __shfl_xor(acc[j], 32, 64);
    if (l < 32) {
        uint4 rv = *(const uint4*)&res16[(size_t)n * HC12 + c];
        u32 rw[4] = {rv.x, rv.y, rv.z, rv.w};
        float4 b0 = *(const float4*)&bias[c];
        float4 b1v = *(const float4*)&bias[c + 4];
        float bb[8] = {b0.x, b0.y, b0.z, b0.w, b1v.x, b1v.y, b1v.z, b1v.w};
        union { u16 u[8]; uint4 v; } p;
#pragma unroll
        for (int j = 0; j < 8; j++) {
            float rf = h2f((u16)((rw[j >> 1] >> ((j & 1) * 16)) & 0xffff));
            float vv = acc[j] * inv + bb[j] + rf;
            float ev2 = vv > 0.f ? vv : expm1f(vv);
            p.u[j] = f2h(ev2);
        }
        *(uint4*)&out16[(size_t)n * ostride + c] = p.v;
    }
}

// ---------------- FUSED layer-3 pre-GEMM aggregate: G[n,h,:] = softmax-weighted sum of h2 ----------------
__global__ __launch_bounds__(256) void agg_fused_g3(u16* __restrict__ hG,
                                                    const int* __restrict__ rowp,
                                                    const int* __restrict__ col,
                                                    const float* __restrict__ asrc,
                                                    const float* __restrict__ adst,
                                                    int N) {
    int l = threadIdx.x & 63;
    int n = blockIdx.x * 4 + (threadIdx.x >> 6);
    if (n >= N) return;
    int r0 = rowp[n], r1 = rowp[n + 1];
    int c4 = l * 4;
    int hs = l & 3;             // stats head
    int e_st = l >> 2;          // stats edge slot 0..15
    float ad = adst[n * 4 + hs];
    float m = -3.4e38f, ssum = 0.f;
    float acc[4][4];
#pragma unroll
    for (int h = 0; h < 4; h++)
#pragma unroll
        for (int j = 0; j < 4; j++) acc[h][j] = 0.f;
    for (int kb = r0; kb < r1; kb += 16) {
        int cn = min(16, r1 - kb);
        int cidx = col[kb + (l & 15)];
        // ---- stats phase (online softmax) ----
        int esc = __shfl(cidx, e_st, 64);
        bool ev = e_st < cn;
        float lg = ev ? lrelu(asrc[esc * 4 + hs] + ad) : -3.4e38f;
        float cm = lg;
#pragma unroll
        for (int o = 4; o < 64; o <<= 1) cm = fmaxf(cm, __shfl_xor(cm, o, 64));
        float mn = fmaxf(m, cm);
        float es = __expf(m - mn);
        float atil = ev ? __expf(lg - mn) : 0.f;
        float cs = atil;
#pragma unroll
        for (int o = 4; o < 64; o <<= 1) cs += __shfl_xor(cs, o, 64);
        ssum = ssum * es + cs;
        m = mn;
#pragma unroll
        for (int h = 0; h < 4; h++) {
            float eso = __shfl(es, h, 64);   // lanes 0..3 hold per-head es
#pragma unroll
            for (int j = 0; j < 4; j++) acc[h][j] *= eso;
        }
        // ---- gather phase: row read once, used for all 4 heads ----
        for (int k = 0; k < cn; k++) {
            int src = __shfl(cidx, k, 64);
            float a0 = __shfl(atil, k * 4 + 0, 64);
            float a1 = __shfl(atil, k * 4 + 1, 64);
            float a2 = __shfl(atil, k * 4 + 2, 64);
            float a3 = __shfl(atil, k * 4 + 3, 64);
            uint2 v = *(const uint2*)&hG[(size_t)src * KG3 + c4];
            float x0 = h2f((u16)(v.x & 0xffff));
            float x1 = h2f((u16)(v.x >> 16));
            float x2 = h2f((u16)(v.y & 0xffff));
            float x3 = h2f((u16)(v.y >> 16));
            acc[0][0] += a0 * x0; acc[0][1] += a0 * x1; acc[0][2] += a0 * x2; acc[0][3] += a0 * x3;
            acc[1][0] += a1 * x0; acc[1][1] += a1 * x1; acc[1][2] += a1 * x2; acc[1][3] += a1 * x3;
            acc[2][0] += a2 * x0; acc[2][1] += a2 * x1; acc[2][2] += a2 * x2; acc[2][3] += a2 * x3;
            acc[3][0] += a3 * x0; acc[3][1] += a3 * x1; acc[3][2] += a3 * x2; acc[3][3] += a3 * x3;
        }
    }
    u16* orow = hG + (size_t)n * KG3 + 256;
#pragma unroll
    for (int h = 0; h < 4; h++) {
        float inv = 1.f / (__shfl(ssum, h, 64) + 1e-16f);
        union { u16 u[4]; uint2 v; } p;
#pragma unroll
        for (int j = 0; j < 4; j++) p.u[j] = f2h(acc[h][j] * inv);
        *(uint2*)&orow[h * 256 + c4] = p.v;
    }
}

extern "C" void kernel_launch(void* const* d_in, const int* in_sizes, int n_in,
                              void* d_out, int out_size, void* d_ws, size_t ws_size,
                              hipStream_t stream) {
    const float* x   = (const float*)d_in[0];
    const int*   ei  = (const int*)d_in[1];
    const float* W1  = (const float*)d_in[2];
    const float* a1s = (const float*)d_in[3];
    const float* a1d = (const float*)d_in[4];
    const float* b1  = (const float*)d_in[5];
    const float* l1W = (const float*)d_in[6];
    const float* l1b = (const float*)d_in[7];
    const float* W2  = (const float*)d_in[8];
    const float* a2s = (const float*)d_in[9];
    const float* a2d = (const float*)d_in[10];
    const float* b2  = (const float*)d_in[11];
    const float* W3  = (const float*)d_in[12];
    const float* a3s = (const float*)d_in[13];
    const float* a3d = (const float*)d_in[14];
    const float* b3  = (const float*)d_in[15];
    const float* l3W = (const float*)d_in[16];
    const float* l3b = (const float*)d_in[17];

    const int N = in_sizes[0] / F_IN;   // 50000
    const int E = in_sizes[1] / 2;      // 400000
    const int* srcv = ei;
    const int* dstv = ei + E;

    char* ws = (char*)d_ws;
    size_t off = 0;
    auto alloc = [&](size_t bytes) -> char* {
        char* p = ws + off;
        off += (bytes + 255) & ~(size_t)255;
        return p;
    };
    u16*   hG    = (u16*)alloc((size_t)N * KG3 * 2 + 256);   // [h2 | G] rows, K=1280
    u16*   xh    = (u16*)alloc((size_t)N * HC12 * 2 + 256);
    u16*   x16   = (u16*)alloc((size_t)N * F_IN * 2);
    u16*   h1f   = (u16*)alloc((size_t)N * HC12 * 2);
    u16*   lin1h = (u16*)alloc((size_t)N * HC12 * 2);
    float* as_   = (float*)alloc((size_t)N * 4 * 4);
    float* ad_   = (float*)alloc((size_t)N * 4 * 4);
    int* rowp    = (int*)alloc((size_t)(N + 1) * 4);
    int* degc    = (int*)alloc((size_t)N * 4);
    int* cur     = (int*)alloc((size_t)N * 4);
    int* part    = (int*)alloc((size_t)256 * 4);
    int* col     = (int*)alloc((size_t)E * 4 + 256);
    u16* C1 = (u16*)alloc((size_t)512 * 128 * 2);
    u16* C2 = (u16*)alloc((size_t)256 * 256 * 2);
    u16* C3 = (u16*)alloc((size_t)NCLS * KG3 * 2);
    float* ps = (float*)alloc(1024 * 4);
    float* pd = (float*)alloc(1024 * 4);
    (void)ws_size; (void)n_in; (void)out_size;

    // ---- CSR build (parallel scan) ----
    hipMemsetAsync(degc, 0, (size_t)N * 4, stream);
    hipMemsetAsync(cur, 0, (size_t)N * 4, stream);
    hist_kernel<<<(E + 255) / 256, 256, 0, stream>>>(dstv, degc, E);
    int nb = (N + 1023) / 1024;
    scan_part<<<nb, 256, 0, stream>>>(degc, part, N);
    scan_mid<<<1, 64, 0, stream>>>(part, nb);
    scan_final<<<nb, 256, 0, stream>>>(degc, part, rowp, N);
    scatter_kernel<<<(E + 255) / 256, 256, 0, stream>>>(srcv, dstv, rowp, cur, col, E);

    // ---- weight transpose + projections + x conversion ----
    cvtT_all_kernel<<<(285952 + 255) / 256, 256, 0, stream>>>(W1, l1W, W2, W3, l3W, C1, C2, C3);
    prep3_kernel<<<8, 256, 0, stream>>>(W3, a3s, a3d, ps, pd);
    xcvt_kernel<<<(N * F_IN / 8 + 255) / 256, 256, 0, stream>>>(x, x16, N * F_IN / 8);

    int ny = (N + BM - 1) / BM;
    int wgrid = (N + 3) / 4;

    // ---- layer 1: one GEMM, N=512 (cols 0-255 -> xh f16, 256-511 -> lin1h f16 + l1b) ----
    gemm_f16<<<4 * ny, 256, 0, stream>>>(x16, C1, N, F_IN, 512, 4, ny,
                                         256, xh, 256, lin1h, nullptr, l1b, 256, 1, 0);
    alpha_wave_256<<<wgrid, 256, 0, stream>>>(xh, a1s, a1d, as_, ad_, N);
    agg_fused_256<<<wgrid, 256, 0, stream>>>(xh, rowp, col, as_, ad_, b1, lin1h, h1f, 256, N);

    // ---- layer 2: N=256, residual = h1f; h2 written into hG cols 0-255 (stride 1280) ----
    gemm_f16<<<2 * ny, 256, 0, stream>>>(h1f, C2, N, HC12, 256, 2, ny,
                                         256, xh, 256, nullptr, nullptr, nullptr, 0, 1, 0);
    alpha_wave_256<<<wgrid, 256, 0, stream>>>(xh, a2s, a2d, as_, ad_, N);
    agg_fused_256<<<wgrid, 256, 0, stream>>>(xh, rowp, col, as_, ad_, b2, h1f, hG, KG3, N);

    // ---- layer 3 (restructured): alphas from projected vectors; aggregate h2; split-K GEMM ----
    alpha3_dot<<<wgrid, 256, 0, stream>>>(hG, ps, pd, as_, ad_, N);
    agg_fused_g3<<<wgrid, 256, 0, stream>>>(hG, rowp, col, as_, ad_, N);
    fill_bias_kernel<<<(N * NCLS + 255) / 256, 256, 0, stream>>>((float*)d_out, b3, N * NCLS);
    gemm_f16<<<4 * ny, 256, 0, stream>>>(hG, C3, N, KG3, NCLS, 1, ny,
                                         0, nullptr, 0, nullptr, (float*)d_out, nullptr, NCLS,
                                         4, 1);
}

// Round 11
// 446.724 us; speedup vs baseline: 1.3170x; 1.3170x over previous
//
#include <hip/hip_runtime.h>
#include <cstdint>
#include <cstddef>

#define F_IN 128
#define HC12 256   // HEADS*HID for layers 1/2
#define KG3 1280   // hG row stride (u16): [h2 (256) | G (4x256)]
#define NCLS 121

typedef unsigned short u16;
typedef unsigned int u32;
typedef __attribute__((ext_vector_type(8))) short short8;
typedef __attribute__((ext_vector_type(8))) __fp16 half8;
typedef __attribute__((ext_vector_type(4))) float float4v;

static __device__ __forceinline__ float lrelu(float x) { return x > 0.f ? x : 0.2f * x; }

static __device__ __forceinline__ u16 f2h(float f) {
    union { __fp16 h; u16 u; } v; v.h = (__fp16)f; return v.u;
}
static __device__ __forceinline__ float h2f(u16 u) {
    union { u16 u; __fp16 h; } v; v.u = u; return (float)v.h;
}

static __device__ __forceinline__ void gload16(const u16* g, u16* l) {
    __builtin_amdgcn_global_load_lds((const __attribute__((address_space(1))) void*)g,
                                     (__attribute__((address_space(3))) void*)l,
                                     16, 0, 0);
}

// ---------------- CSR build ----------------
__global__ void hist_kernel(const int* __restrict__ dst, int* __restrict__ deg, int E) {
    int e = blockIdx.x * 256 + threadIdx.x;
    if (e < E) atomicAdd(&deg[dst[e]], 1);
}

__global__ __launch_bounds__(256) void scan_part(const int* __restrict__ deg,
                                                 int* __restrict__ part, int N) {
    int b = blockIdx.x;
    int i0 = b * 1024 + threadIdx.x * 4;
    int t = 0;
    if (i0     < N) t += deg[i0];
    if (i0 + 1 < N) t += deg[i0 + 1];
    if (i0 + 2 < N) t += deg[i0 + 2];
    if (i0 + 3 < N) t += deg[i0 + 3];
#pragma unroll
    for (int o = 1; o < 64; o <<= 1) t += __shfl_xor(t, o, 64);
    __shared__ int sw[4];
    int w = threadIdx.x >> 6, lane = threadIdx.x & 63;
    if (!lane) sw[w] = t;
    __syncthreads();
    if (threadIdx.x == 0) part[b] = sw[0] + sw[1] + sw[2] + sw[3];
}

__global__ void scan_mid(int* __restrict__ part, int nb) {
    int lane = threadIdx.x;   // 64 threads
    __shared__ int carry_s;
    if (lane == 0) carry_s = 0;
    __syncthreads();
    for (int base = 0; base < nb; base += 64) {
        int i = base + lane;
        int v = (i < nb) ? part[i] : 0;
        int sc = v;
#pragma unroll
        for (int o = 1; o < 64; o <<= 1) {
            int u = __shfl_up(sc, o, 64);
            if (lane >= o) sc += u;
        }
        int carry = carry_s;
        if (i < nb) part[i] = carry + sc - v;   // exclusive prefix
        __syncthreads();
        if (lane == 63) carry_s = carry + sc;
        __syncthreads();
    }
}

__global__ __launch_bounds__(256) void scan_final(const int* __restrict__ deg,
                                                  const int* __restrict__ part,
                                                  int* __restrict__ rowp, int N) {
    int b = blockIdx.x;
    int tid = threadIdx.x;
    int w = tid >> 6, lane = tid & 63;
    int i0 = b * 1024 + tid * 4;
    int v0 = (i0     < N) ? deg[i0]     : 0;
    int v1 = (i0 + 1 < N) ? deg[i0 + 1] : 0;
    int v2 = (i0 + 2 < N) ? deg[i0 + 2] : 0;
    int v3 = (i0 + 3 < N) ? deg[i0 + 3] : 0;
    int t = v0 + v1 + v2 + v3;
    int sc = t;
#pragma unroll
    for (int o = 1; o < 64; o <<= 1) {
        int u = __shfl_up(sc, o, 64);
        if (lane >= o) sc += u;
    }
    __shared__ int sw2[4];
    if (lane == 63) sw2[w] = sc;
    __syncthreads();
    int cw = 0;
    for (int x = 0; x < w; x++) cw += sw2[x];
    int tb = part[b] + cw + sc - t;
    if (i0     < N) rowp[i0 + 1] = tb + v0;
    if (i0 + 1 < N) rowp[i0 + 2] = tb + v0 + v1;
    if (i0 + 2 < N) rowp[i0 + 3] = tb + v0 + v1 + v2;
    if (i0 + 3 < N) rowp[i0 + 4] = tb + t;
    if (b == 0 && tid == 0) rowp[0] = 0;
}

__global__ void scatter_kernel(const int* __restrict__ src, const int* __restrict__ dst,
                               const int* __restrict__ rowp, int* __restrict__ cur,
                               int* __restrict__ col, int E) {
    int e = blockIdx.x * 256 + threadIdx.x;
    if (e < E) {
        int d = dst[e];
        int pos = rowp[d] + atomicAdd(&cur[d], 1);
        col[pos] = src[e];
    }
}

// ---------------- fused weight transpose to f16 ----------------
// C3 = combined [121 cols][1280 K] weight: rows 0-255 = lin3W, rows 256+h*256+k = 0.25*W3[k, h*121+c]
__global__ void cvtT_all_kernel(const float* W1, const float* l1W, const float* W2,
                                const float* W3, const float* l3W,
                                u16* C1, u16* C2, u16* C3) {
    int i = blockIdx.x * 256 + threadIdx.x;
    if (i >= 285952) return;
    if (i >= 131072) {
        int j = i - 131072;          // 0 .. 154879 = 121*1280
        int c = j % NCLS, k = j / NCLS;
        float v;
        if (k < 256) v = l3W[(size_t)k * NCLS + c];
        else {
            int kp = k - 256;
            v = 0.25f * W3[(size_t)(kp & 255) * 484 + (kp >> 8) * NCLS + c];
        }
        C3[(size_t)c * KG3 + k] = f2h(v);
        return;
    }
    const float* B; u16* o; int K, N;
    if (i < 32768)      { B = W1;  o = C1;             K = 128; N = 256; }
    else if (i < 65536) { B = l1W; o = C1 + 256 * 128; K = 128; N = 256; i -= 32768; }
    else                { B = W2;  o = C2;             K = 256; N = 256; i -= 65536; }
    int n = i % N, k = i / N;
    o[(size_t)n * K + k] = f2h(B[(size_t)k * N + n]);
}

// ---------------- projected layer-3 attention vectors: p[h] = W3[:,h-block] @ a3 ----------------
__global__ __launch_bounds__(256) void prep3_kernel(const float* __restrict__ W3,
                                                    const float* __restrict__ a3s,
                                                    const float* __restrict__ a3d,
                                                    float* __restrict__ ps,
                                                    float* __restrict__ pd) {
    int idx = blockIdx.x * 256 + threadIdx.x;   // 2048 items: t(2) x h(4) x k(256)
    if (idx >= 2048) return;
    int t = idx >> 10, h = (idx >> 8) & 3, k = idx & 255;
    const float* a = t ? a3d : a3s;
    const float* wrow = W3 + (size_t)k * 484 + h * NCLS;
    const float* arow = a + h * NCLS;
    float s = 0.f;
    for (int c = 0; c < NCLS; c++) s += wrow[c] * arow[c];
    (t ? pd : ps)[h * 256 + k] = s;
}

// ---------------- x fp32 -> f16 ----------------
__global__ __launch_bounds__(256) void xcvt_kernel(const float* __restrict__ x,
                                                   u16* __restrict__ o, int total8) {
    int i = blockIdx.x * 256 + threadIdx.x;
    if (i >= total8) return;
    const float4* p = (const float4*)(x + (size_t)i * 8);
    float4 a = p[0], b = p[1];
    union { u16 u[8]; short8 v; } r;
    r.u[0] = f2h(a.x); r.u[1] = f2h(a.y); r.u[2] = f2h(a.z); r.u[3] = f2h(a.w);
    r.u[4] = f2h(b.x); r.u[5] = f2h(b.y); r.u[6] = f2h(b.z); r.u[7] = f2h(b.w);
    *(short8*)(o + (size_t)i * 8) = r.v;
}

// ---------------- f16 MFMA GEMM, 128x128 tile, global_load_lds staging ----------------
#define BM 128
#define BN 128
#define BK 32

__global__ __launch_bounds__(256, 3) void gemm_f16(const u16* __restrict__ A16,
                                                   const u16* __restrict__ BT,
                                                   int M, int K, int Ntot,
                                                   int nx, int ny,
                                                   int Nb, u16* __restrict__ Cb, int strideB,
                                                   u16* __restrict__ Cf16,
                                                   float* __restrict__ Cf32,
                                                   const float* __restrict__ biasf, int strideF) {
    __shared__ __align__(16) u16 sA[BM * BK];
    __shared__ __align__(16) u16 sB[BN * BK];
    int tid = threadIdx.x;
    int wave = tid >> 6, lane = tid & 63;
    int wr = wave >> 1, wc = wave & 1;

    // XCD-aware block swizzle
    int bid = blockIdx.x;
    int G = nx * 8;
    int g = bid / G;
    int rem = ny - g * 8;
    int rb, cb;
    if (rem >= 8) {
        int r = bid - g * G;
        rb = g * 8 + (r & 7);
        cb = r >> 3;
    } else {
        int t = bid - g * G;
        rb = g * 8 + t % rem;
        cb = t / rem;
    }
    int m0 = rb * BM, n0 = cb * BN;

    int fm = lane & 15;
    int q = lane >> 4;

    int srow = lane >> 2;
    int sch = (lane & 3) * 8;
    u16* lA0 = &sA[(wave * 32) * BK];
    u16* lA1 = &sA[(wave * 32 + 16) * BK];
    u16* lB0 = &sB[(wave * 32) * BK];
    u16* lB1 = &sB[(wave * 32 + 16) * BK];
    int ar0 = min(m0 + wave * 32 + srow, M - 1);
    int ar1 = min(m0 + wave * 32 + 16 + srow, M - 1);
    int br0 = min(n0 + wave * 32 + srow, Ntot - 1);
    int br1 = min(n0 + wave * 32 + 16 + srow, Ntot - 1);

    float4v acc[4][4];
#pragma unroll
    for (int i = 0; i < 4; i++)
#pragma unroll
        for (int j = 0; j < 4; j++) acc[i][j] = (float4v){0.f, 0.f, 0.f, 0.f};

    for (int kc = 0; kc < K; kc += BK) {
        gload16(&A16[(size_t)ar0 * K + kc + sch], lA0);
        gload16(&A16[(size_t)ar1 * K + kc + sch], lA1);
        gload16(&BT[(size_t)br0 * K + kc + sch], lB0);
        gload16(&BT[(size_t)br1 * K + kc + sch], lB1);
        __syncthreads();

        half8 ah[4];
#pragma unroll
        for (int mi = 0; mi < 4; mi++)
            ah[mi] = *(const half8*)&sA[(wr * 64 + mi * 16 + fm) * BK + q * 8];
#pragma unroll
        for (int ni = 0; ni < 4; ni++) {
            half8 bh = *(const half8*)&sB[(wc * 64 + ni * 16 + fm) * BK + q * 8];
#pragma unroll
            for (int mi = 0; mi < 4; mi++)
                acc[mi][ni] = __builtin_amdgcn_mfma_f32_16x16x32_f16(ah[mi], bh, acc[mi][ni], 0, 0, 0);
        }
        __syncthreads();
    }

#pragma unroll
    for (int mi = 0; mi < 4; mi++) {
#pragma unroll
        for (int ni = 0; ni < 4; ni++) {
            int colg = n0 + wc * 64 + ni * 16 + fm;
            if (colg >= Ntot) continue;
#pragma unroll
            for (int r = 0; r < 4; r++) {
                int rowg = m0 + wr * 64 + mi * 16 + q * 4 + r;
                if (rowg >= M) continue;
                float v = acc[mi][ni][r];
                if (colg < Nb) {
                    Cb[(size_t)rowg * strideB + colg] = f2h(v);
                } else {
                    int cf = colg - Nb;
                    float vb = v + biasf[cf];
                    if (Cf32) Cf32[(size_t)rowg * strideF + cf] = vb;
                    else      Cf16[(size_t)rowg * strideF + cf] = f2h(vb);
                }
            }
        }
    }
}

// ---------------- tall-skinny final GEMM: M x 1280 @ 1280 x 121, BK=128, XOR-swizzled LDS ----------------
// 10 K-iterations (vs 40), 64 MFMA per barrier. LDS chunk swizzle: 16B-chunk c of row r stored
// at c ^ (r&7) -- applied to pre-swizzled GLOBAL source (linear gload dest) and to ds_read addr.
#define TBK 128

__global__ __launch_bounds__(256, 2) void gemm_tall(const u16* __restrict__ A16,
                                                    const u16* __restrict__ BT,
                                                    int M,
                                                    float* __restrict__ out,
                                                    const float* __restrict__ b3) {
    __shared__ __align__(16) u16 sA[128 * TBK];
    __shared__ __align__(16) u16 sB[128 * TBK];
    int tid = threadIdx.x;
    int wave = tid >> 6, lane = tid & 63;
    int wr = wave >> 1, wc = wave & 1;
    int m0 = blockIdx.x * 128;
    int fm = lane & 15, q = lane >> 4;

    // staging: instruction g covers 4 rows (wave*32+g*4); lane l -> row +(l>>4), dest chunk l&15.
    int srow = lane >> 4;          // 0..3
    int dch = lane & 15;           // dest 16B-chunk within row

    float4v acc[4][4];
#pragma unroll
    for (int i = 0; i < 4; i++)
#pragma unroll
        for (int j = 0; j < 4; j++) acc[i][j] = (float4v){0.f, 0.f, 0.f, 0.f};

    for (int kc = 0; kc < KG3; kc += TBK) {
#pragma unroll
        for (int g = 0; g < 8; g++) {
            int rA = wave * 32 + g * 4 + srow;
            int sch = (dch ^ (rA & 7)) * 8;        // pre-swizzled source chunk (u16 units)
            int arow = min(m0 + rA, M - 1);
            gload16(&A16[(size_t)arow * KG3 + kc + sch], &sA[(wave * 32 + g * 4) * TBK]);
            int brow = min(rA, NCLS - 1);
            int schB = (dch ^ (rA & 7)) * 8;
            gload16(&BT[(size_t)brow * KG3 + kc + schB], &sB[(wave * 32 + g * 4) * TBK]);
        }
        __syncthreads();

#pragma unroll
        for (int kk = 0; kk < 4; kk++) {
            int cch = kk * 4 + q;                  // logical 16B-chunk for this K-slice
            half8 ah[4];
#pragma unroll
            for (int mi = 0; mi < 4; mi++) {
                int r = wr * 64 + mi * 16 + fm;
                ah[mi] = *(const half8*)&sA[r * TBK + (cch ^ (r & 7)) * 8];
            }
#pragma unroll
            for (int ni = 0; ni < 4; ni++) {
                int rn = wc * 64 + ni * 16 + fm;
                half8 bh = *(const half8*)&sB[rn * TBK + (cch ^ (rn & 7)) * 8];
#pragma unroll
                for (int mi = 0; mi < 4; mi++)
                    acc[mi][ni] = __builtin_amdgcn_mfma_f32_16x16x32_f16(ah[mi], bh, acc[mi][ni], 0, 0, 0);
            }
        }
        __syncthreads();
    }

#pragma unroll
    for (int mi = 0; mi < 4; mi++) {
#pragma unroll
        for (int ni = 0; ni < 4; ni++) {
            int colg = wc * 64 + ni * 16 + fm;
            if (colg >= NCLS) continue;
            float bb = b3[colg];
#pragma unroll
            for (int r = 0; r < 4; r++) {
                int rowg = m0 + wr * 64 + mi * 16 + q * 4 + r;
                if (rowg >= M) continue;
                out[(size_t)rowg * NCLS + colg] = acc[mi][ni][r] + bb;
            }
        }
    }
}

// ---------------- wave-per-node attention coefficients, C=64 (layers 1/2) ----------------
__global__ __launch_bounds__(256) void alpha_wave_256(const u16* __restrict__ xh,
                                                      const float* __restrict__ a_s,
                                                      const float* __restrict__ a_d,
                                                      float* __restrict__ as_o,
                                                      float* __restrict__ ad_o, int N) {
    int lane = threadIdx.x & 63;
    int n = blockIdx.x * 4 + (threadIdx.x >> 6);
    if (n >= N) return;
    int c = lane * 4;
    uint2 v = *(const uint2*)&xh[(size_t)n * HC12 + c];
    float4 s4 = *(const float4*)&a_s[c];
    float4 d4 = *(const float4*)&a_d[c];
    float x0 = h2f((u16)(v.x & 0xffff)), x1 = h2f((u16)(v.x >> 16));
    float x2 = h2f((u16)(v.y & 0xffff)), x3 = h2f((u16)(v.y >> 16));
    float ss = x0 * s4.x + x1 * s4.y + x2 * s4.z + x3 * s4.w;
    float sd = x0 * d4.x + x1 * d4.y + x2 * d4.z + x3 * d4.w;
#pragma unroll
    for (int o = 1; o < 16; o <<= 1) {
        ss += __shfl_xor(ss, o, 64);
        sd += __shfl_xor(sd, o, 64);
    }
    if ((lane & 15) == 0) {
        as_o[n * 4 + (lane >> 4)] = ss;
        ad_o[n * 4 + (lane >> 4)] = sd;
    }
}

// ---------------- layer-3 attention coefficients from h2 via projected vectors ----------------
__global__ __launch_bounds__(256) void alpha3_dot(const u16* __restrict__ hG,
                                                  const float* __restrict__ ps,
                                                  const float* __restrict__ pd,
                                                  float* __restrict__ as_o,
                                                  float* __restrict__ ad_o, int N) {
    int l = threadIdx.x & 63;
    int n = blockIdx.x * 4 + (threadIdx.x >> 6);
    if (n >= N) return;
    int h = l >> 4, li = l & 15;
    int c = li * 16;
    const u16* row = hG + (size_t)n * KG3 + c;
    uint4 v0 = *(const uint4*)&row[0];
    uint4 v1 = *(const uint4*)&row[8];
    u32 ww[8] = {v0.x, v0.y, v0.z, v0.w, v1.x, v1.y, v1.z, v1.w};
    const float* psr = ps + h * 256 + c;
    const float* pdr = pd + h * 256 + c;
    float ss = 0.f, sd = 0.f;
#pragma unroll
    for (int j = 0; j < 8; j++) {
        float lo = h2f((u16)(ww[j] & 0xffff));
        float hi = h2f((u16)(ww[j] >> 16));
        ss += lo * psr[2 * j] + hi * psr[2 * j + 1];
        sd += lo * pdr[2 * j] + hi * pdr[2 * j + 1];
    }
#pragma unroll
    for (int o = 1; o < 16; o <<= 1) {
        ss += __shfl_xor(ss, o, 64);
        sd += __shfl_xor(sd, o, 64);
    }
    if (li == 0) {
        as_o[n * 4 + h] = ss;
        ad_o[n * 4 + h] = sd;
    }
}

// ---------------- FUSED online-softmax aggregate, HC=256 (layers 1/2) ----------------
__global__ __launch_bounds__(256) void agg_fused_256(const u16* __restrict__ xh,
                                                     const int* __restrict__ rowp,
                                                     const int* __restrict__ col,
                                                     const float* __restrict__ asrc,
                                                     const float* __restrict__ adst,
                                                     const float* __restrict__ bias,
                                                     const u16* __restrict__ res16,
                                                     u16* __restrict__ out16, int ostride,
                                                     int N) {
    int l = threadIdx.x & 63;
    int n = blockIdx.x * 4 + (threadIdx.x >> 6);
    if (n >= N) return;
    int r0 = rowp[n], r1 = rowp[n + 1];
    int s_slot = l >> 5, li = l & 31;
    int c = li * 8;
    int h = li >> 3;            // own head (gather role)
    int hs = l & 3;             // stats head
    int e_st = l >> 2;          // stats edge slot 0..15
    float ad = adst[n * 4 + hs];
    float m = -3.4e38f, ssum = 0.f;
    float acc[8] = {0.f, 0.f, 0.f, 0.f, 0.f, 0.f, 0.f, 0.f};
    for (int kb = r0; kb < r1; kb += 16) {
        int cn = min(16, r1 - kb);
        int cidx = col[kb + (l & 15)];
        // ---- stats phase (online softmax) ----
        int esc = __shfl(cidx, e_st, 64);
        bool ev = e_st < cn;
        float lg = ev ? lrelu(asrc[esc * 4 + hs] + ad) : -3.4e38f;
        float cm = lg;
#pragma unroll
        for (int o = 4; o < 64; o <<= 1) cm = fmaxf(cm, __shfl_xor(cm, o, 64));
        float mn = fmaxf(m, cm);
        float es = __expf(m - mn);
        float atil = ev ? __expf(lg - mn) : 0.f;
        float cs = atil;
#pragma unroll
        for (int o = 4; o < 64; o <<= 1) cs += __shfl_xor(cs, o, 64);
        ssum = ssum * es + cs;
        m = mn;
        float eso = __shfl(es, (l & 60) | h, 64);   // rescale for own head
#pragma unroll
        for (int j = 0; j < 8; j++) acc[j] *= eso;
        // ---- gather phase ----
        int npair = (cn + 1) >> 1;
#pragma unroll 4
        for (int k = 0; k < npair; k++) {
            int e = 2 * k + s_slot;
            int em = e < cn ? e : cn - 1;
            int src = __shfl(cidx, em, 64);
            float al = __shfl(atil, em * 4 + h, 64);
            if (e >= cn) al = 0.f;
            uint4 v = *(const uint4*)&xh[(size_t)src * HC12 + c];
            acc[0] += al * h2f((u16)(v.x & 0xffff));
            acc[1] += al * h2f((u16)(v.x >> 16));
            acc[2] += al * h2f((u16)(v.y & 0xffff));
            acc[3] += al * h2f((u16)(v.y >> 16));
            acc[4] += al * h2f((u16)(v.z & 0xffff));
            acc[5] += al * h2f((u16)(v.z >> 16));
            acc[6] += al * h2f((u16)(v.w & 0xffff));
            acc[7] += al * h2f((u16)(v.w >> 16));
        }
    }
    float sso = __shfl(ssum, (l & 60) | h, 64);
    float inv = 1.f / (sso + 1e-16f);
#pragma unroll
    for (int j = 0; j < 8; j++) acc[j] += __shfl_xor(acc[j], 32, 64);
    if (l < 32) {
        uint4 rv = *(const uint4*)&res16[(size_t)n * HC12 + c];
        u32 rw[4] = {rv.x, rv.y, rv.z, rv.w};
        float4 b0 = *(const float4*)&bias[c];
        float4 b1v = *(const float4*)&bias[c + 4];
        float bb[8] = {b0.x, b0.y, b0.z, b0.w, b1v.x, b1v.y, b1v.z, b1v.w};
        union { u16 u[8]; uint4 v; } p;
#pragma unroll
        for (int j = 0; j < 8; j++) {
            float rf = h2f((u16)((rw[j >> 1] >> ((j & 1) * 16)) & 0xffff));
            float vv = acc[j] * inv + bb[j] + rf;
            float ev2 = vv > 0.f ? vv : expm1f(vv);
            p.u[j] = f2h(ev2);
        }
        *(uint4*)&out16[(size_t)n * ostride + c] = p.v;
    }
}

// ---------------- FUSED layer-3 pre-GEMM aggregate: G[n,h,:] = softmax-weighted sum of h2 ----------------
__global__ __launch_bounds__(256) void agg_fused_g3(u16* __restrict__ hG,
                                                    const int* __restrict__ rowp,
                                                    const int* __restrict__ col,
                                                    const float* __restrict__ asrc,
                                                    const float* __restrict__ adst,
                                                    int N) {
    int l = threadIdx.x & 63;
    int n = blockIdx.x * 4 + (threadIdx.x >> 6);
    if (n >= N) return;
    int r0 = rowp[n], r1 = rowp[n + 1];
    int c4 = l * 4;
    int hs = l & 3;             // stats head
    int e_st = l >> 2;          // stats edge slot 0..15
    float ad = adst[n * 4 + hs];
    float m = -3.4e38f, ssum = 0.f;
    float acc[4][4];
#pragma unroll
    for (int h = 0; h < 4; h++)
#pragma unroll
        for (int j = 0; j < 4; j++) acc[h][j] = 0.f;
    for (int kb = r0; kb < r1; kb += 16) {
        int cn = min(16, r1 - kb);
        int cidx = col[kb + (l & 15)];
        // ---- stats phase (online softmax) ----
        int esc = __shfl(cidx, e_st, 64);
        bool ev = e_st < cn;
        float lg = ev ? lrelu(asrc[esc * 4 + hs] + ad) : -3.4e38f;
        float cm = lg;
#pragma unroll
        for (int o = 4; o < 64; o <<= 1) cm = fmaxf(cm, __shfl_xor(cm, o, 64));
        float mn = fmaxf(m, cm);
        float es = __expf(m - mn);
        float atil = ev ? __expf(lg - mn) : 0.f;
        float cs = atil;
#pragma unroll
        for (int o = 4; o < 64; o <<= 1) cs += __shfl_xor(cs, o, 64);
        ssum = ssum * es + cs;
        m = mn;
#pragma unroll
        for (int h = 0; h < 4; h++) {
            float eso = __shfl(es, h, 64);   // lanes 0..3 hold per-head es
#pragma unroll
            for (int j = 0; j < 4; j++) acc[h][j] *= eso;
        }
        // ---- gather phase: row read once, used for all 4 heads ----
        for (int k = 0; k < cn; k++) {
            int src = __shfl(cidx, k, 64);
            float a0 = __shfl(atil, k * 4 + 0, 64);
            float a1 = __shfl(atil, k * 4 + 1, 64);
            float a2 = __shfl(atil, k * 4 + 2, 64);
            float a3 = __shfl(atil, k * 4 + 3, 64);
            uint2 v = *(const uint2*)&hG[(size_t)src * KG3 + c4];
            float x0 = h2f((u16)(v.x & 0xffff));
            float x1 = h2f((u16)(v.x >> 16));
            float x2 = h2f((u16)(v.y & 0xffff));
            float x3 = h2f((u16)(v.y >> 16));
            acc[0][0] += a0 * x0; acc[0][1] += a0 * x1; acc[0][2] += a0 * x2; acc[0][3] += a0 * x3;
            acc[1][0] += a1 * x0; acc[1][1] += a1 * x1; acc[1][2] += a1 * x2; acc[1][3] += a1 * x3;
            acc[2][0] += a2 * x0; acc[2][1] += a2 * x1; acc[2][2] += a2 * x2; acc[2][3] += a2 * x3;
            acc[3][0] += a3 * x0; acc[3][1] += a3 * x1; acc[3][2] += a3 * x2; acc[3][3] += a3 * x3;
        }
    }
    u16* orow = hG + (size_t)n * KG3 + 256;
#pragma unroll
    for (int h = 0; h < 4; h++) {
        float inv = 1.f / (__shfl(ssum, h, 64) + 1e-16f);
        union { u16 u[4]; uint2 v; } p;
#pragma unroll
        for (int j = 0; j < 4; j++) p.u[j] = f2h(acc[h][j] * inv);
        *(uint2*)&orow[h * 256 + c4] = p.v;
    }
}

extern "C" void kernel_launch(void* const* d_in, const int* in_sizes, int n_in,
                              void* d_out, int out_size, void* d_ws, size_t ws_size,
                              hipStream_t stream) {
    const float* x   = (const float*)d_in[0];
    const int*   ei  = (const int*)d_in[1];
    const float* W1  = (const float*)d_in[2];
    const float* a1s = (const float*)d_in[3];
    const float* a1d = (const float*)d_in[4];
    const float* b1  = (const float*)d_in[5];
    const float* l1W = (const float*)d_in[6];
    const float* l1b = (const float*)d_in[7];
    const float* W2  = (const float*)d_in[8];
    const float* a2s = (const float*)d_in[9];
    const float* a2d = (const float*)d_in[10];
    const float* b2  = (const float*)d_in[11];
    const float* W3  = (const float*)d_in[12];
    const float* a3s = (const float*)d_in[13];
    const float* a3d = (const float*)d_in[14];
    const float* b3  = (const float*)d_in[15];
    const float* l3W = (const float*)d_in[16];
    const float* l3b = (const float*)d_in[17];

    const int N = in_sizes[0] / F_IN;   // 50000
    const int E = in_sizes[1] / 2;      // 400000
    const int* srcv = ei;
    const int* dstv = ei + E;

    char* ws = (char*)d_ws;
    size_t off = 0;
    auto alloc = [&](size_t bytes) -> char* {
        char* p = ws + off;
        off += (bytes + 255) & ~(size_t)255;
        return p;
    };
    u16*   hG    = (u16*)alloc((size_t)N * KG3 * 2 + 256);   // [h2 | G] rows, K=1280
    u16*   xh    = (u16*)alloc((size_t)N * HC12 * 2 + 256);
    u16*   x16   = (u16*)alloc((size_t)N * F_IN * 2);
    u16*   h1f   = (u16*)alloc((size_t)N * HC12 * 2);
    u16*   lin1h = (u16*)alloc((size_t)N * HC12 * 2);
    float* as_   = (float*)alloc((size_t)N * 4 * 4);
    float* ad_   = (float*)alloc((size_t)N * 4 * 4);
    int* rowp    = (int*)alloc((size_t)(N + 1) * 4);
    int* degc    = (int*)alloc((size_t)N * 4);
    int* cur     = (int*)alloc((size_t)N * 4);
    int* part    = (int*)alloc((size_t)256 * 4);
    int* col     = (int*)alloc((size_t)E * 4 + 256);
    u16* C1 = (u16*)alloc((size_t)512 * 128 * 2);
    u16* C2 = (u16*)alloc((size_t)256 * 256 * 2);
    u16* C3 = (u16*)alloc((size_t)NCLS * KG3 * 2);
    float* ps = (float*)alloc(1024 * 4);
    float* pd = (float*)alloc(1024 * 4);
    (void)ws_size; (void)n_in; (void)out_size;

    // ---- CSR build (parallel scan) ----
    hipMemsetAsync(degc, 0, (size_t)N * 4, stream);
    hipMemsetAsync(cur, 0, (size_t)N * 4, stream);
    hist_kernel<<<(E + 255) / 256, 256, 0, stream>>>(dstv, degc, E);
    int nb = (N + 1023) / 1024;
    scan_part<<<nb, 256, 0, stream>>>(degc, part, N);
    scan_mid<<<1, 64, 0, stream>>>(part, nb);
    scan_final<<<nb, 256, 0, stream>>>(degc, part, rowp, N);
    scatter_kernel<<<(E + 255) / 256, 256, 0, stream>>>(srcv, dstv, rowp, cur, col, E);

    // ---- weight transpose + projections + x conversion ----
    cvtT_all_kernel<<<(285952 + 255) / 256, 256, 0, stream>>>(W1, l1W, W2, W3, l3W, C1, C2, C3);
    prep3_kernel<<<8, 256, 0, stream>>>(W3, a3s, a3d, ps, pd);
    xcvt_kernel<<<(N * F_IN / 8 + 255) / 256, 256, 0, stream>>>(x, x16, N * F_IN / 8);

    int ny = (N + BM - 1) / BM;
    int wgrid = (N + 3) / 4;

    // ---- layer 1: one GEMM, N=512 (cols 0-255 -> xh f16, 256-511 -> lin1h f16 + l1b) ----
    gemm_f16<<<4 * ny, 256, 0, stream>>>(x16, C1, N, F_IN, 512, 4, ny,
                                         256, xh, 256, lin1h, nullptr, l1b, 256);
    alpha_wave_256<<<wgrid, 256, 0, stream>>>(xh, a1s, a1d, as_, ad_, N);
    agg_fused_256<<<wgrid, 256, 0, stream>>>(xh, rowp, col, as_, ad_, b1, lin1h, h1f, 256, N);

    // ---- layer 2: N=256, residual = h1f; h2 written into hG cols 0-255 (stride 1280) ----
    gemm_f16<<<2 * ny, 256, 0, stream>>>(h1f, C2, N, HC12, 256, 2, ny,
                                         256, xh, 256, nullptr, nullptr, nullptr, 0);
    alpha_wave_256<<<wgrid, 256, 0, stream>>>(xh, a2s, a2d, as_, ad_, N);
    agg_fused_256<<<wgrid, 256, 0, stream>>>(xh, rowp, col, as_, ad_, b2, h1f, hG, KG3, N);

    // ---- layer 3 (restructured): alphas from projected vectors; aggregate h2; tall GEMM ----
    alpha3_dot<<<wgrid, 256, 0, stream>>>(hG, ps, pd, as_, ad_, N);
    agg_fused_g3<<<wgrid, 256, 0, stream>>>(hG, rowp, col, as_, ad_, N);
    gemm_tall<<<ny, 256, 0, stream>>>(hG, C3, N, (float*)d_out, b3);
}

// Round 12
// 444.238 us; speedup vs baseline: 1.3243x; 1.0056x over previous
//
#include <hip/hip_runtime.h>
#include <cstdint>
#include <cstddef>

#define F_IN 128
#define HC12 256   // HEADS*HID for layers 1/2
#define KG3 1280   // logical K for final GEMM: [h2 (256) | G (4x256)]
#define NCLS 121

typedef unsigned short u16;
typedef unsigned int u32;
typedef __attribute__((ext_vector_type(8))) short short8;
typedef __attribute__((ext_vector_type(8))) __fp16 half8;
typedef __attribute__((ext_vector_type(4))) float float4v;

static __device__ __forceinline__ float lrelu(float x) { return x > 0.f ? x : 0.2f * x; }

static __device__ __forceinline__ u16 f2h(float f) {
    union { __fp16 h; u16 u; } v; v.h = (__fp16)f; return v.u;
}
static __device__ __forceinline__ float h2f(u16 u) {
    union { u16 u; __fp16 h; } v; v.u = u; return (float)v.h;
}

static __device__ __forceinline__ void gload16(const u16* g, u16* l) {
    __builtin_amdgcn_global_load_lds((const __attribute__((address_space(1))) void*)g,
                                     (__attribute__((address_space(3))) void*)l,
                                     16, 0, 0);
}

// ---------------- CSR build ----------------
__global__ void hist_kernel(const int* __restrict__ dst, int* __restrict__ deg, int E) {
    int e = blockIdx.x * 256 + threadIdx.x;
    if (e < E) atomicAdd(&deg[dst[e]], 1);
}

__global__ __launch_bounds__(256) void scan_part(const int* __restrict__ deg,
                                                 int* __restrict__ part, int N) {
    int b = blockIdx.x;
    int i0 = b * 1024 + threadIdx.x * 4;
    int t = 0;
    if (i0     < N) t += deg[i0];
    if (i0 + 1 < N) t += deg[i0 + 1];
    if (i0 + 2 < N) t += deg[i0 + 2];
    if (i0 + 3 < N) t += deg[i0 + 3];
#pragma unroll
    for (int o = 1; o < 64; o <<= 1) t += __shfl_xor(t, o, 64);
    __shared__ int sw[4];
    int w = threadIdx.x >> 6, lane = threadIdx.x & 63;
    if (!lane) sw[w] = t;
    __syncthreads();
    if (threadIdx.x == 0) part[b] = sw[0] + sw[1] + sw[2] + sw[3];
}

__global__ void scan_mid(int* __restrict__ part, int nb) {
    int lane = threadIdx.x;   // 64 threads
    __shared__ int carry_s;
    if (lane == 0) carry_s = 0;
    __syncthreads();
    for (int base = 0; base < nb; base += 64) {
        int i = base + lane;
        int v = (i < nb) ? part[i] : 0;
        int sc = v;
#pragma unroll
        for (int o = 1; o < 64; o <<= 1) {
            int u = __shfl_up(sc, o, 64);
            if (lane >= o) sc += u;
        }
        int carry = carry_s;
        if (i < nb) part[i] = carry + sc - v;   // exclusive prefix
        __syncthreads();
        if (lane == 63) carry_s = carry + sc;
        __syncthreads();
    }
}

__global__ __launch_bounds__(256) void scan_final(const int* __restrict__ deg,
                                                  const int* __restrict__ part,
                                                  int* __restrict__ rowp, int N) {
    int b = blockIdx.x;
    int tid = threadIdx.x;
    int w = tid >> 6, lane = tid & 63;
    int i0 = b * 1024 + tid * 4;
    int v0 = (i0     < N) ? deg[i0]     : 0;
    int v1 = (i0 + 1 < N) ? deg[i0 + 1] : 0;
    int v2 = (i0 + 2 < N) ? deg[i0 + 2] : 0;
    int v3 = (i0 + 3 < N) ? deg[i0 + 3] : 0;
    int t = v0 + v1 + v2 + v3;
    int sc = t;
#pragma unroll
    for (int o = 1; o < 64; o <<= 1) {
        int u = __shfl_up(sc, o, 64);
        if (lane >= o) sc += u;
    }
    __shared__ int sw2[4];
    if (lane == 63) sw2[w] = sc;
    __syncthreads();
    int cw = 0;
    for (int x = 0; x < w; x++) cw += sw2[x];
    int tb = part[b] + cw + sc - t;
    if (i0     < N) rowp[i0 + 1] = tb + v0;
    if (i0 + 1 < N) rowp[i0 + 2] = tb + v0 + v1;
    if (i0 + 2 < N) rowp[i0 + 3] = tb + v0 + v1 + v2;
    if (i0 + 3 < N) rowp[i0 + 4] = tb + t;
    if (b == 0 && tid == 0) rowp[0] = 0;
}

__global__ void scatter_kernel(const int* __restrict__ src, const int* __restrict__ dst,
                               const int* __restrict__ rowp, int* __restrict__ cur,
                               int* __restrict__ col, int E) {
    int e = blockIdx.x * 256 + threadIdx.x;
    if (e < E) {
        int d = dst[e];
        int pos = rowp[d] + atomicAdd(&cur[d], 1);
        col[pos] = src[e];
    }
}

// ---------------- fused weight transpose to f16 ----------------
// C3 = combined [121 cols][1280 K] weight: rows 0-255 = lin3W, rows 256+h*256+k = 0.25*W3[k, h*121+c]
__global__ void cvtT_all_kernel(const float* W1, const float* l1W, const float* W2,
                                const float* W3, const float* l3W,
                                u16* C1, u16* C2, u16* C3) {
    int i = blockIdx.x * 256 + threadIdx.x;
    if (i >= 285952) return;
    if (i >= 131072) {
        int j = i - 131072;          // 0 .. 154879 = 121*1280
        int c = j % NCLS, k = j / NCLS;
        float v;
        if (k < 256) v = l3W[(size_t)k * NCLS + c];
        else {
            int kp = k - 256;
            v = 0.25f * W3[(size_t)(kp & 255) * 484 + (kp >> 8) * NCLS + c];
        }
        C3[(size_t)c * KG3 + k] = f2h(v);
        return;
    }
    const float* B; u16* o; int K, N;
    if (i < 32768)      { B = W1;  o = C1;             K = 128; N = 256; }
    else if (i < 65536) { B = l1W; o = C1 + 256 * 128; K = 128; N = 256; i -= 32768; }
    else                { B = W2;  o = C2;             K = 256; N = 256; i -= 65536; }
    int n = i % N, k = i / N;
    o[(size_t)n * K + k] = f2h(B[(size_t)k * N + n]);
}

// ---------------- projected layer-3 attention vectors: p[h] = W3[:,h-block] @ a3 ----------------
__global__ __launch_bounds__(256) void prep3_kernel(const float* __restrict__ W3,
                                                    const float* __restrict__ a3s,
                                                    const float* __restrict__ a3d,
                                                    float* __restrict__ ps,
                                                    float* __restrict__ pd) {
    int idx = blockIdx.x * 256 + threadIdx.x;   // 2048 items: t(2) x h(4) x k(256)
    if (idx >= 2048) return;
    int t = idx >> 10, h = (idx >> 8) & 3, k = idx & 255;
    const float* a = t ? a3d : a3s;
    const float* wrow = W3 + (size_t)k * 484 + h * NCLS;
    const float* arow = a + h * NCLS;
    float s = 0.f;
    for (int c = 0; c < NCLS; c++) s += wrow[c] * arow[c];
    (t ? pd : ps)[h * 256 + k] = s;
}

// ---------------- x fp32 -> f16 ----------------
__global__ __launch_bounds__(256) void xcvt_kernel(const float* __restrict__ x,
                                                   u16* __restrict__ o, int total8) {
    int i = blockIdx.x * 256 + threadIdx.x;
    if (i >= total8) return;
    const float4* p = (const float4*)(x + (size_t)i * 8);
    float4 a = p[0], b = p[1];
    union { u16 u[8]; short8 v; } r;
    r.u[0] = f2h(a.x); r.u[1] = f2h(a.y); r.u[2] = f2h(a.z); r.u[3] = f2h(a.w);
    r.u[4] = f2h(b.x); r.u[5] = f2h(b.y); r.u[6] = f2h(b.z); r.u[7] = f2h(b.w);
    *(short8*)(o + (size_t)i * 8) = r.v;
}

// ---------------- f16 MFMA GEMM, 128x128 tile, global_load_lds staging ----------------
#define BM 128
#define BN 128
#define BK 32

__global__ __launch_bounds__(256, 3) void gemm_f16(const u16* __restrict__ A16,
                                                   const u16* __restrict__ BT,
                                                   int M, int K, int Ntot,
                                                   int nx, int ny,
                                                   int Nb, u16* __restrict__ Cb, int strideB,
                                                   u16* __restrict__ Cf16,
                                                   float* __restrict__ Cf32,
                                                   const float* __restrict__ biasf, int strideF) {
    __shared__ __align__(16) u16 sA[BM * BK];
    __shared__ __align__(16) u16 sB[BN * BK];
    int tid = threadIdx.x;
    int wave = tid >> 6, lane = tid & 63;
    int wr = wave >> 1, wc = wave & 1;

    // XCD-aware block swizzle
    int bid = blockIdx.x;
    int G = nx * 8;
    int g = bid / G;
    int rem = ny - g * 8;
    int rb, cb;
    if (rem >= 8) {
        int r = bid - g * G;
        rb = g * 8 + (r & 7);
        cb = r >> 3;
    } else {
        int t = bid - g * G;
        rb = g * 8 + t % rem;
        cb = t / rem;
    }
    int m0 = rb * BM, n0 = cb * BN;

    int fm = lane & 15;
    int q = lane >> 4;

    int srow = lane >> 2;
    int sch = (lane & 3) * 8;
    u16* lA0 = &sA[(wave * 32) * BK];
    u16* lA1 = &sA[(wave * 32 + 16) * BK];
    u16* lB0 = &sB[(wave * 32) * BK];
    u16* lB1 = &sB[(wave * 32 + 16) * BK];
    int ar0 = min(m0 + wave * 32 + srow, M - 1);
    int ar1 = min(m0 + wave * 32 + 16 + srow, M - 1);
    int br0 = min(n0 + wave * 32 + srow, Ntot - 1);
    int br1 = min(n0 + wave * 32 + 16 + srow, Ntot - 1);

    float4v acc[4][4];
#pragma unroll
    for (int i = 0; i < 4; i++)
#pragma unroll
        for (int j = 0; j < 4; j++) acc[i][j] = (float4v){0.f, 0.f, 0.f, 0.f};

    for (int kc = 0; kc < K; kc += BK) {
        gload16(&A16[(size_t)ar0 * K + kc + sch], lA0);
        gload16(&A16[(size_t)ar1 * K + kc + sch], lA1);
        gload16(&BT[(size_t)br0 * K + kc + sch], lB0);
        gload16(&BT[(size_t)br1 * K + kc + sch], lB1);
        __syncthreads();

        half8 ah[4];
#pragma unroll
        for (int mi = 0; mi < 4; mi++)
            ah[mi] = *(const half8*)&sA[(wr * 64 + mi * 16 + fm) * BK + q * 8];
#pragma unroll
        for (int ni = 0; ni < 4; ni++) {
            half8 bh = *(const half8*)&sB[(wc * 64 + ni * 16 + fm) * BK + q * 8];
#pragma unroll
            for (int mi = 0; mi < 4; mi++)
                acc[mi][ni] = __builtin_amdgcn_mfma_f32_16x16x32_f16(ah[mi], bh, acc[mi][ni], 0, 0, 0);
        }
        __syncthreads();
    }

#pragma unroll
    for (int mi = 0; mi < 4; mi++) {
#pragma unroll
        for (int ni = 0; ni < 4; ni++) {
            int colg = n0 + wc * 64 + ni * 16 + fm;
            if (colg >= Ntot) continue;
#pragma unroll
            for (int r = 0; r < 4; r++) {
                int rowg = m0 + wr * 64 + mi * 16 + q * 4 + r;
                if (rowg >= M) continue;
                float v = acc[mi][ni][r];
                if (colg < Nb) {
                    Cb[(size_t)rowg * strideB + colg] = f2h(v);
                } else {
                    int cf = colg - Nb;
                    float vb = v + biasf[cf];
                    if (Cf32) Cf32[(size_t)rowg * strideF + cf] = vb;
                    else      Cf16[(size_t)rowg * strideF + cf] = f2h(vb);
                }
            }
        }
    }
}

// ---------------- tall-skinny final GEMM: M x 1280 @ 1280 x 121, BK=128, XOR-swizzled LDS ----------------
// A-rows are split across h2c (cols 0-255) and Gc (cols 256-1279); per k-iteration the
// source buffer is uniform (kc<256 -> h2c). 10 K-iterations, 64 MFMA per barrier.
#define TBK 128

__global__ __launch_bounds__(256, 2) void gemm_tall(const u16* __restrict__ h2c,
                                                    const u16* __restrict__ Gc,
                                                    const u16* __restrict__ BT,
                                                    int M,
                                                    float* __restrict__ out,
                                                    const float* __restrict__ b3) {
    __shared__ __align__(16) u16 sA[128 * TBK];
    __shared__ __align__(16) u16 sB[128 * TBK];
    int tid = threadIdx.x;
    int wave = tid >> 6, lane = tid & 63;
    int wr = wave >> 1, wc = wave & 1;
    int m0 = blockIdx.x * 128;
    int fm = lane & 15, q = lane >> 4;

    int srow = lane >> 4;          // 0..3
    int dch = lane & 15;           // dest 16B-chunk within row

    float4v acc[4][4];
#pragma unroll
    for (int i = 0; i < 4; i++)
#pragma unroll
        for (int j = 0; j < 4; j++) acc[i][j] = (float4v){0.f, 0.f, 0.f, 0.f};

    for (int kc = 0; kc < KG3; kc += TBK) {
        const u16* asrc; int astride, aoff;
        if (kc < 256) { asrc = h2c; astride = 256;  aoff = kc; }
        else          { asrc = Gc;  astride = 1024; aoff = kc - 256; }
#pragma unroll
        for (int g = 0; g < 8; g++) {
            int rA = wave * 32 + g * 4 + srow;
            int sch = (dch ^ (rA & 7)) * 8;        // pre-swizzled source chunk (u16 units)
            int arow = min(m0 + rA, M - 1);
            gload16(&asrc[(size_t)arow * astride + aoff + sch], &sA[(wave * 32 + g * 4) * TBK]);
            int brow = min(rA, NCLS - 1);
            gload16(&BT[(size_t)brow * KG3 + kc + sch], &sB[(wave * 32 + g * 4) * TBK]);
        }
        __syncthreads();

#pragma unroll
        for (int kk = 0; kk < 4; kk++) {
            int cch = kk * 4 + q;                  // logical 16B-chunk for this K-slice
            half8 ah[4];
#pragma unroll
            for (int mi = 0; mi < 4; mi++) {
                int r = wr * 64 + mi * 16 + fm;
                ah[mi] = *(const half8*)&sA[r * TBK + (cch ^ (r & 7)) * 8];
            }
#pragma unroll
            for (int ni = 0; ni < 4; ni++) {
                int rn = wc * 64 + ni * 16 + fm;
                half8 bh = *(const half8*)&sB[rn * TBK + (cch ^ (rn & 7)) * 8];
#pragma unroll
                for (int mi = 0; mi < 4; mi++)
                    acc[mi][ni] = __builtin_amdgcn_mfma_f32_16x16x32_f16(ah[mi], bh, acc[mi][ni], 0, 0, 0);
            }
        }
        __syncthreads();
    }

#pragma unroll
    for (int mi = 0; mi < 4; mi++) {
#pragma unroll
        for (int ni = 0; ni < 4; ni++) {
            int colg = wc * 64 + ni * 16 + fm;
            if (colg >= NCLS) continue;
            float bb = b3[colg];
#pragma unroll
            for (int r = 0; r < 4; r++) {
                int rowg = m0 + wr * 64 + mi * 16 + q * 4 + r;
                if (rowg >= M) continue;
                out[(size_t)rowg * NCLS + colg] = acc[mi][ni][r] + bb;
            }
        }
    }
}

// ---------------- wave-per-node attention coefficients, C=64 (layers 1/2) ----------------
__global__ __launch_bounds__(256) void alpha_wave_256(const u16* __restrict__ xh,
                                                      const float* __restrict__ a_s,
                                                      const float* __restrict__ a_d,
                                                      float* __restrict__ as_o,
                                                      float* __restrict__ ad_o, int N) {
    int lane = threadIdx.x & 63;
    int n = blockIdx.x * 4 + (threadIdx.x >> 6);
    if (n >= N) return;
    int c = lane * 4;
    uint2 v = *(const uint2*)&xh[(size_t)n * HC12 + c];
    float4 s4 = *(const float4*)&a_s[c];
    float4 d4 = *(const float4*)&a_d[c];
    float x0 = h2f((u16)(v.x & 0xffff)), x1 = h2f((u16)(v.x >> 16));
    float x2 = h2f((u16)(v.y & 0xffff)), x3 = h2f((u16)(v.y >> 16));
    float ss = x0 * s4.x + x1 * s4.y + x2 * s4.z + x3 * s4.w;
    float sd = x0 * d4.x + x1 * d4.y + x2 * d4.z + x3 * d4.w;
#pragma unroll
    for (int o = 1; o < 16; o <<= 1) {
        ss += __shfl_xor(ss, o, 64);
        sd += __shfl_xor(sd, o, 64);
    }
    if ((lane & 15) == 0) {
        as_o[n * 4 + (lane >> 4)] = ss;
        ad_o[n * 4 + (lane >> 4)] = sd;
    }
}

// ---------------- layer-3 attention coefficients from compact h2 via projected vectors ----------------
__global__ __launch_bounds__(256) void alpha3_dot(const u16* __restrict__ h2c,
                                                  const float* __restrict__ ps,
                                                  const float* __restrict__ pd,
                                                  float* __restrict__ as_o,
                                                  float* __restrict__ ad_o, int N) {
    int l = threadIdx.x & 63;
    int n = blockIdx.x * 4 + (threadIdx.x >> 6);
    if (n >= N) return;
    int h = l >> 4, li = l & 15;
    int c = li * 16;
    const u16* row = h2c + (size_t)n * HC12 + c;
    uint4 v0 = *(const uint4*)&row[0];
    uint4 v1 = *(const uint4*)&row[8];
    u32 ww[8] = {v0.x, v0.y, v0.z, v0.w, v1.x, v1.y, v1.z, v1.w};
    const float* psr = ps + h * 256 + c;
    const float* pdr = pd + h * 256 + c;
    float ss = 0.f, sd = 0.f;
#pragma unroll
    for (int j = 0; j < 8; j++) {
        float lo = h2f((u16)(ww[j] & 0xffff));
        float hi = h2f((u16)(ww[j] >> 16));
        ss += lo * psr[2 * j] + hi * psr[2 * j + 1];
        sd += lo * pdr[2 * j] + hi * pdr[2 * j + 1];
    }
#pragma unroll
    for (int o = 1; o < 16; o <<= 1) {
        ss += __shfl_xor(ss, o, 64);
        sd += __shfl_xor(sd, o, 64);
    }
    if (li == 0) {
        as_o[n * 4 + h] = ss;
        ad_o[n * 4 + h] = sd;
    }
}

// ---------------- FUSED online-softmax aggregate, HC=256 (layers 1/2) ----------------
__global__ __launch_bounds__(256) void agg_fused_256(const u16* __restrict__ xh,
                                                     const int* __restrict__ rowp,
                                                     const int* __restrict__ col,
                                                     const float* __restrict__ asrc,
                                                     const float* __restrict__ adst,
                                                     const float* __restrict__ bias,
                                                     const u16* __restrict__ res16,
                                                     u16* __restrict__ out16,
                                                     int N) {
    int l = threadIdx.x & 63;
    int n = blockIdx.x * 4 + (threadIdx.x >> 6);
    if (n >= N) return;
    int r0 = rowp[n], r1 = rowp[n + 1];
    int s_slot = l >> 5, li = l & 31;
    int c = li * 8;
    int h = li >> 3;            // own head (gather role)
    int hs = l & 3;             // stats head
    int e_st = l >> 2;          // stats edge slot 0..15
    float ad = adst[n * 4 + hs];
    float m = -3.4e38f, ssum = 0.f;
    float acc[8] = {0.f, 0.f, 0.f, 0.f, 0.f, 0.f, 0.f, 0.f};
    for (int kb = r0; kb < r1; kb += 16) {
        int cn = min(16, r1 - kb);
        int cidx = col[kb + (l & 15)];
        // ---- stats phase (online softmax) ----
        int esc = __shfl(cidx, e_st, 64);
        bool ev = e_st < cn;
        float lg = ev ? lrelu(asrc[esc * 4 + hs] + ad) : -3.4e38f;
        float cm = lg;
#pragma unroll
        for (int o = 4; o < 64; o <<= 1) cm = fmaxf(cm, __shfl_xor(cm, o, 64));
        float mn = fmaxf(m, cm);
        float es = __expf(m - mn);
        float atil = ev ? __expf(lg - mn) : 0.f;
        float cs = atil;
#pragma unroll
        for (int o = 4; o < 64; o <<= 1) cs += __shfl_xor(cs, o, 64);
        ssum = ssum * es + cs;
        m = mn;
        float eso = __shfl(es, (l & 60) | h, 64);   // rescale for own head
#pragma unroll
        for (int j = 0; j < 8; j++) acc[j] *= eso;
        // ---- gather phase ----
        int npair = (cn + 1) >> 1;
#pragma unroll 4
        for (int k = 0; k < npair; k++) {
            int e = 2 * k + s_slot;
            int em = e < cn ? e : cn - 1;
            int src = __shfl(cidx, em, 64);
            float al = __shfl(atil, em * 4 + h, 64);
            if (e >= cn) al = 0.f;
            uint4 v = *(const uint4*)&xh[(size_t)src * HC12 + c];
            acc[0] += al * h2f((u16)(v.x & 0xffff));
            acc[1] += al * h2f((u16)(v.x >> 16));
            acc[2] += al * h2f((u16)(v.y & 0xffff));
            acc[3] += al * h2f((u16)(v.y >> 16));
            acc[4] += al * h2f((u16)(v.z & 0xffff));
            acc[5] += al * h2f((u16)(v.z >> 16));
            acc[6] += al * h2f((u16)(v.w & 0xffff));
            acc[7] += al * h2f((u16)(v.w >> 16));
        }
    }
    float sso = __shfl(ssum, (l & 60) | h, 64);
    float inv = 1.f / (sso + 1e-16f);
#pragma unroll
    for (int j = 0; j < 8; j++) acc[j] += __shfl_xor(acc[j], 32, 64);
    if (l < 32) {
        uint4 rv = *(const uint4*)&res16[(size_t)n * HC12 + c];
        u32 rw[4] = {rv.x, rv.y, rv.z, rv.w};
        float4 b0 = *(const float4*)&bias[c];
        float4 b1v = *(const float4*)&bias[c + 4];
        float bb[8] = {b0.x, b0.y, b0.z, b0.w, b1v.x, b1v.y, b1v.z, b1v.w};
        union { u16 u[8]; uint4 v; } p;
#pragma unroll
        for (int j = 0; j < 8; j++) {
            float rf = h2f((u16)((rw[j >> 1] >> ((j & 1) * 16)) & 0xffff));
            float vv = acc[j] * inv + bb[j] + rf;
            float ev2 = vv > 0.f ? vv : expm1f(vv);
            p.u[j] = f2h(ev2);
        }
        *(uint4*)&out16[(size_t)n * HC12 + c] = p.v;
    }
}

// ---------------- FUSED layer-3 pre-GEMM aggregate: Gc[n,h,:] = softmax-weighted sum of h2c ----------------
// Wave per node; lane owns 4 channels c4=l*4 of compact h2c (8 B load, row read once per wave),
// accumulates for all 4 heads; 2-edge unrolled gather for load-level parallelism.
__global__ __launch_bounds__(256) void agg_fused_g3(const u16* __restrict__ h2c,
                                                    u16* __restrict__ Gc,
                                                    const int* __restrict__ rowp,
                                                    const int* __restrict__ col,
                                                    const float* __restrict__ asrc,
                                                    const float* __restrict__ adst,
                                                    int N) {
    int l = threadIdx.x & 63;
    int n = blockIdx.x * 4 + (threadIdx.x >> 6);
    if (n >= N) return;
    int r0 = rowp[n], r1 = rowp[n + 1];
    int c4 = l * 4;
    int hs = l & 3;             // stats head
    int e_st = l >> 2;          // stats edge slot 0..15
    float ad = adst[n * 4 + hs];
    float m = -3.4e38f, ssum = 0.f;
    float acc[4][4];
#pragma unroll
    for (int h = 0; h < 4; h++)
#pragma unroll
        for (int j = 0; j < 4; j++) acc[h][j] = 0.f;
    for (int kb = r0; kb < r1; kb += 16) {
        int cn = min(16, r1 - kb);
        int cidx = col[kb + (l & 15)];
        // ---- stats phase (online softmax) ----
        int esc = __shfl(cidx, e_st, 64);
        bool ev = e_st < cn;
        float lg = ev ? lrelu(asrc[esc * 4 + hs] + ad) : -3.4e38f;
        float cm = lg;
#pragma unroll
        for (int o = 4; o < 64; o <<= 1) cm = fmaxf(cm, __shfl_xor(cm, o, 64));
        float mn = fmaxf(m, cm);
        float es = __expf(m - mn);
        float atil = ev ? __expf(lg - mn) : 0.f;
        float cs = atil;
#pragma unroll
        for (int o = 4; o < 64; o <<= 1) cs += __shfl_xor(cs, o, 64);
        ssum = ssum * es + cs;
        m = mn;
#pragma unroll
        for (int h = 0; h < 4; h++) {
            float eso = __shfl(es, h, 64);   // lanes 0..3 hold per-head es
#pragma unroll
            for (int j = 0; j < 4; j++) acc[h][j] *= eso;
        }
        // ---- gather phase: 2 edges in flight, row read once, all 4 heads ----
        int k = 0;
        for (; k + 1 < cn; k += 2) {
            int s0 = __shfl(cidx, k, 64);
            int s1 = __shfl(cidx, k + 1, 64);
            uint2 v0 = *(const uint2*)&h2c[(size_t)s0 * HC12 + c4];
            uint2 v1 = *(const uint2*)&h2c[(size_t)s1 * HC12 + c4];
            float a00 = __shfl(atil, k * 4 + 0, 64);
            float a01 = __shfl(atil, k * 4 + 1, 64);
            float a02 = __shfl(atil, k * 4 + 2, 64);
            float a03 = __shfl(atil, k * 4 + 3, 64);
            float a10 = __shfl(atil, k * 4 + 4, 64);
            float a11 = __shfl(atil, k * 4 + 5, 64);
            float a12 = __shfl(atil, k * 4 + 6, 64);
            float a13 = __shfl(atil, k * 4 + 7, 64);
            float x0 = h2f((u16)(v0.x & 0xffff)), x1 = h2f((u16)(v0.x >> 16));
            float x2 = h2f((u16)(v0.y & 0xffff)), x3 = h2f((u16)(v0.y >> 16));
            float y0 = h2f((u16)(v1.x & 0xffff)), y1 = h2f((u16)(v1.x >> 16));
            float y2 = h2f((u16)(v1.y & 0xffff)), y3 = h2f((u16)(v1.y >> 16));
            acc[0][0] += a00 * x0 + a10 * y0; acc[0][1] += a00 * x1 + a10 * y1;
            acc[0][2] += a00 * x2 + a10 * y2; acc[0][3] += a00 * x3 + a10 * y3;
            acc[1][0] += a01 * x0 + a11 * y0; acc[1][1] += a01 * x1 + a11 * y1;
            acc[1][2] += a01 * x2 + a11 * y2; acc[1][3] += a01 * x3 + a11 * y3;
            acc[2][0] += a02 * x0 + a12 * y0; acc[2][1] += a02 * x1 + a12 * y1;
            acc[2][2] += a02 * x2 + a12 * y2; acc[2][3] += a02 * x3 + a12 * y3;
            acc[3][0] += a03 * x0 + a13 * y0; acc[3][1] += a03 * x1 + a13 * y1;
            acc[3][2] += a03 * x2 + a13 * y2; acc[3][3] += a03 * x3 + a13 * y3;
        }
        if (k < cn) {
            int src = __shfl(cidx, k, 64);
            float a0 = __shfl(atil, k * 4 + 0, 64);
            float a1 = __shfl(atil, k * 4 + 1, 64);
            float a2 = __shfl(atil, k * 4 + 2, 64);
            float a3 = __shfl(atil, k * 4 + 3, 64);
            uint2 v = *(const uint2*)&h2c[(size_t)src * HC12 + c4];
            float x0 = h2f((u16)(v.x & 0xffff));
            float x1 = h2f((u16)(v.x >> 16));
            float x2 = h2f((u16)(v.y & 0xffff));
            float x3 = h2f((u16)(v.y >> 16));
            acc[0][0] += a0 * x0; acc[0][1] += a0 * x1; acc[0][2] += a0 * x2; acc[0][3] += a0 * x3;
            acc[1][0] += a1 * x0; acc[1][1] += a1 * x1; acc[1][2] += a1 * x2; acc[1][3] += a1 * x3;
            acc[2][0] += a2 * x0; acc[2][1] += a2 * x1; acc[2][2] += a2 * x2; acc[2][3] += a2 * x3;
            acc[3][0] += a3 * x0; acc[3][1] += a3 * x1; acc[3][2] += a3 * x2; acc[3][3] += a3 * x3;
        }
    }
    u16* orow = Gc + (size_t)n * 1024;
#pragma unroll
    for (int h = 0; h < 4; h++) {
        float inv = 1.f / (__shfl(ssum, h, 64) + 1e-16f);
        union { u16 u[4]; uint2 v; } p;
#pragma unroll
        for (int j = 0; j < 4; j++) p.u[j] = f2h(acc[h][j] * inv);
        *(uint2*)&orow[h * 256 + c4] = p.v;
    }
}

extern "C" void kernel_launch(void* const* d_in, const int* in_sizes, int n_in,
                              void* d_out, int out_size, void* d_ws, size_t ws_size,
                              hipStream_t stream) {
    const float* x   = (const float*)d_in[0];
    const int*   ei  = (const int*)d_in[1];
    const float* W1  = (const float*)d_in[2];
    const float* a1s = (const float*)d_in[3];
    const float* a1d = (const float*)d_in[4];
    const float* b1  = (const float*)d_in[5];
    const float* l1W = (const float*)d_in[6];
    const float* l1b = (const float*)d_in[7];
    const float* W2  = (const float*)d_in[8];
    const float* a2s = (const float*)d_in[9];
    const float* a2d = (const float*)d_in[10];
    const float* b2  = (const float*)d_in[11];
    const float* W3  = (const float*)d_in[12];
    const float* a3s = (const float*)d_in[13];
    const float* a3d = (const float*)d_in[14];
    const float* b3  = (const float*)d_in[15];
    const float* l3W = (const float*)d_in[16];
    const float* l3b = (const float*)d_in[17];

    const int N = in_sizes[0] / F_IN;   // 50000
    const int E = in_sizes[1] / 2;      // 400000
    const int* srcv = ei;
    const int* dstv = ei + E;

    char* ws = (char*)d_ws;
    size_t off = 0;
    auto alloc = [&](size_t bytes) -> char* {
        char* p = ws + off;
        off += (bytes + 255) & ~(size_t)255;
        return p;
    };
    u16*   h2c   = (u16*)alloc((size_t)N * HC12 * 2 + 256);   // compact h2 (L3-resident gather table)
    u16*   Gc    = (u16*)alloc((size_t)N * 1024 * 2 + 256);   // aggregated G, 4 heads x 256
    u16*   xh    = (u16*)alloc((size_t)N * HC12 * 2 + 256);
    u16*   x16   = (u16*)alloc((size_t)N * F_IN * 2);
    u16*   h1f   = (u16*)alloc((size_t)N * HC12 * 2);
    u16*   lin1h = (u16*)alloc((size_t)N * HC12 * 2);
    float* as_   = (float*)alloc((size_t)N * 4 * 4);
    float* ad_   = (float*)alloc((size_t)N * 4 * 4);
    int* rowp    = (int*)alloc((size_t)(N + 1) * 4);
    int* degc    = (int*)alloc((size_t)N * 4);
    int* cur     = (int*)alloc((size_t)N * 4);
    int* part    = (int*)alloc((size_t)256 * 4);
    int* col     = (int*)alloc((size_t)E * 4 + 256);
    u16* C1 = (u16*)alloc((size_t)512 * 128 * 2);
    u16* C2 = (u16*)alloc((size_t)256 * 256 * 2);
    u16* C3 = (u16*)alloc((size_t)NCLS * KG3 * 2);
    float* ps = (float*)alloc(1024 * 4);
    float* pd = (float*)alloc(1024 * 4);
    (void)ws_size; (void)n_in; (void)out_size;

    // ---- CSR build (parallel scan) ----
    hipMemsetAsync(degc, 0, (size_t)N * 4, stream);
    hipMemsetAsync(cur, 0, (size_t)N * 4, stream);
    hist_kernel<<<(E + 255) / 256, 256, 0, stream>>>(dstv, degc, E);
    int nb = (N + 1023) / 1024;
    scan_part<<<nb, 256, 0, stream>>>(degc, part, N);
    scan_mid<<<1, 64, 0, stream>>>(part, nb);
    scan_final<<<nb, 256, 0, stream>>>(degc, part, rowp, N);
    scatter_kernel<<<(E + 255) / 256, 256, 0, stream>>>(srcv, dstv, rowp, cur, col, E);

    // ---- weight transpose + projections + x conversion ----
    cvtT_all_kernel<<<(285952 + 255) / 256, 256, 0, stream>>>(W1, l1W, W2, W3, l3W, C1, C2, C3);
    prep3_kernel<<<8, 256, 0, stream>>>(W3, a3s, a3d, ps, pd);
    xcvt_kernel<<<(N * F_IN / 8 + 255) / 256, 256, 0, stream>>>(x, x16, N * F_IN / 8);

    int ny = (N + BM - 1) / BM;
    int wgrid = (N + 3) / 4;

    // ---- layer 1: one GEMM, N=512 (cols 0-255 -> xh f16, 256-511 -> lin1h f16 + l1b) ----
    gemm_f16<<<4 * ny, 256, 0, stream>>>(x16, C1, N, F_IN, 512, 4, ny,
                                         256, xh, 256, lin1h, nullptr, l1b, 256);
    alpha_wave_256<<<wgrid, 256, 0, stream>>>(xh, a1s, a1d, as_, ad_, N);
    agg_fused_256<<<wgrid, 256, 0, stream>>>(xh, rowp, col, as_, ad_, b1, lin1h, h1f, N);

    // ---- layer 2: N=256, residual = h1f; h2 written compact to h2c ----
    gemm_f16<<<2 * ny, 256, 0, stream>>>(h1f, C2, N, HC12, 256, 2, ny,
                                         256, xh, 256, nullptr, nullptr, nullptr, 0);
    alpha_wave_256<<<wgrid, 256, 0, stream>>>(xh, a2s, a2d, as_, ad_, N);
    agg_fused_256<<<wgrid, 256, 0, stream>>>(xh, rowp, col, as_, ad_, b2, h1f, h2c, N);

    // ---- layer 3 (restructured): alphas from projected vectors; aggregate h2c; tall GEMM ----
    alpha3_dot<<<wgrid, 256, 0, stream>>>(h2c, ps, pd, as_, ad_, N);
    agg_fused_g3<<<wgrid, 256, 0, stream>>>(h2c, Gc, rowp, col, as_, ad_, N);
    gemm_tall<<<ny, 256, 0, stream>>>(h2c, Gc, C3, N, (float*)d_out, b3);
}

// Round 13
// 438.072 us; speedup vs baseline: 1.3430x; 1.0141x over previous
//
#include <hip/hip_runtime.h>
#include <cstdint>
#include <cstddef>

#define F_IN 128
#define HC12 256   // HEADS*HID for layers 1/2
#define KG3 1280   // logical K for final GEMM: [h2 (256) | G (4x256)]
#define NCLS 121

typedef unsigned short u16;
typedef unsigned int u32;
typedef __attribute__((ext_vector_type(8))) short short8;
typedef __attribute__((ext_vector_type(8))) __fp16 half8;
typedef __attribute__((ext_vector_type(4))) float float4v;

static __device__ __forceinline__ float lrelu(float x) { return x > 0.f ? x : 0.2f * x; }

static __device__ __forceinline__ u16 f2h(float f) {
    union { __fp16 h; u16 u; } v; v.h = (__fp16)f; return v.u;
}
static __device__ __forceinline__ float h2f(u16 u) {
    union { u16 u; __fp16 h; } v; v.u = u; return (float)v.h;
}

static __device__ __forceinline__ void gload16(const u16* g, u16* l) {
    __builtin_amdgcn_global_load_lds((const __attribute__((address_space(1))) void*)g,
                                     (__attribute__((address_space(3))) void*)l,
                                     16, 0, 0);
}

// ---------------- CSR build ----------------
__global__ void hist_kernel(const int* __restrict__ dst, int* __restrict__ deg, int E) {
    int e = blockIdx.x * 256 + threadIdx.x;
    if (e < E) atomicAdd(&deg[dst[e]], 1);
}

__global__ __launch_bounds__(256) void scan_part(const int* __restrict__ deg,
                                                 int* __restrict__ part, int N) {
    int b = blockIdx.x;
    int i0 = b * 1024 + threadIdx.x * 4;
    int t = 0;
    if (i0     < N) t += deg[i0];
    if (i0 + 1 < N) t += deg[i0 + 1];
    if (i0 + 2 < N) t += deg[i0 + 2];
    if (i0 + 3 < N) t += deg[i0 + 3];
#pragma unroll
    for (int o = 1; o < 64; o <<= 1) t += __shfl_xor(t, o, 64);
    __shared__ int sw[4];
    int w = threadIdx.x >> 6, lane = threadIdx.x & 63;
    if (!lane) sw[w] = t;
    __syncthreads();
    if (threadIdx.x == 0) part[b] = sw[0] + sw[1] + sw[2] + sw[3];
}

__global__ void scan_mid(int* __restrict__ part, int nb) {
    int lane = threadIdx.x;   // 64 threads
    __shared__ int carry_s;
    if (lane == 0) carry_s = 0;
    __syncthreads();
    for (int base = 0; base < nb; base += 64) {
        int i = base + lane;
        int v = (i < nb) ? part[i] : 0;
        int sc = v;
#pragma unroll
        for (int o = 1; o < 64; o <<= 1) {
            int u = __shfl_up(sc, o, 64);
            if (lane >= o) sc += u;
        }
        int carry = carry_s;
        if (i < nb) part[i] = carry + sc - v;   // exclusive prefix
        __syncthreads();
        if (lane == 63) carry_s = carry + sc;
        __syncthreads();
    }
}

__global__ __launch_bounds__(256) void scan_final(const int* __restrict__ deg,
                                                  const int* __restrict__ part,
                                                  int* __restrict__ rowp, int N) {
    int b = blockIdx.x;
    int tid = threadIdx.x;
    int w = tid >> 6, lane = tid & 63;
    int i0 = b * 1024 + tid * 4;
    int v0 = (i0     < N) ? deg[i0]     : 0;
    int v1 = (i0 + 1 < N) ? deg[i0 + 1] : 0;
    int v2 = (i0 + 2 < N) ? deg[i0 + 2] : 0;
    int v3 = (i0 + 3 < N) ? deg[i0 + 3] : 0;
    int t = v0 + v1 + v2 + v3;
    int sc = t;
#pragma unroll
    for (int o = 1; o < 64; o <<= 1) {
        int u = __shfl_up(sc, o, 64);
        if (lane >= o) sc += u;
    }
    __shared__ int sw2[4];
    if (lane == 63) sw2[w] = sc;
    __syncthreads();
    int cw = 0;
    for (int x = 0; x < w; x++) cw += sw2[x];
    int tb = part[b] + cw + sc - t;
    if (i0     < N) rowp[i0 + 1] = tb + v0;
    if (i0 + 1 < N) rowp[i0 + 2] = tb + v0 + v1;
    if (i0 + 2 < N) rowp[i0 + 3] = tb + v0 + v1 + v2;
    if (i0 + 3 < N) rowp[i0 + 4] = tb + t;
    if (b == 0 && tid == 0) rowp[0] = 0;
}

__global__ void scatter_kernel(const int* __restrict__ src, const int* __restrict__ dst,
                               const int* __restrict__ rowp, int* __restrict__ cur,
                               int* __restrict__ col, int E) {
    int e = blockIdx.x * 256 + threadIdx.x;
    if (e < E) {
        int d = dst[e];
        int pos = rowp[d] + atomicAdd(&cur[d], 1);
        col[pos] = src[e];
    }
}

// ---------------- fused setup: weight transpose + prep3 projection + x conversion ----------------
// ranges: [0,285952) weight cvt; [285952,288000) prep3 (2048); [288000,288000+NF8) xcvt
__global__ void setup_all_kernel(const float* W1, const float* l1W, const float* W2,
                                 const float* W3, const float* l3W,
                                 const float* a3s, const float* a3d,
                                 const float* x,
                                 u16* C1, u16* C2, u16* C3,
                                 float* ps, float* pd,
                                 u16* x16, int NF8) {
    int i = blockIdx.x * 256 + threadIdx.x;
    if (i < 131072) {
        const float* B; u16* o; int K, N;
        if (i < 32768)      { B = W1;  o = C1;             K = 128; N = 256; }
        else if (i < 65536) { B = l1W; o = C1 + 256 * 128; K = 128; N = 256; i -= 32768; }
        else                { B = W2;  o = C2;             K = 256; N = 256; i -= 65536; }
        int n = i % N, k = i / N;
        o[(size_t)n * K + k] = f2h(B[(size_t)k * N + n]);
    } else if (i < 285952) {
        int j = i - 131072;          // 0 .. 154879 = 121*1280
        int c = j % NCLS, k = j / NCLS;
        float v;
        if (k < 256) v = l3W[(size_t)k * NCLS + c];
        else {
            int kp = k - 256;
            v = 0.25f * W3[(size_t)(kp & 255) * 484 + (kp >> 8) * NCLS + c];
        }
        C3[(size_t)c * KG3 + k] = f2h(v);
    } else if (i < 288000) {
        int idx = i - 285952;        // 2048: t(2) x h(4) x k(256)
        int t = idx >> 10, h = (idx >> 8) & 3, k = idx & 255;
        const float* a = t ? a3d : a3s;
        const float* wrow = W3 + (size_t)k * 484 + h * NCLS;
        const float* arow = a + h * NCLS;
        float s = 0.f;
        for (int c = 0; c < NCLS; c++) s += wrow[c] * arow[c];
        (t ? pd : ps)[h * 256 + k] = s;
    } else {
        int j = i - 288000;
        if (j >= NF8) return;
        const float4* p = (const float4*)(x + (size_t)j * 8);
        float4 a = p[0], b = p[1];
        union { u16 u[8]; short8 v; } r;
        r.u[0] = f2h(a.x); r.u[1] = f2h(a.y); r.u[2] = f2h(a.z); r.u[3] = f2h(a.w);
        r.u[4] = f2h(b.x); r.u[5] = f2h(b.y); r.u[6] = f2h(b.z); r.u[7] = f2h(b.w);
        *(short8*)(x16 + (size_t)j * 8) = r.v;
    }
}

// ---------------- f16 MFMA GEMM, 128x128 tile, global_load_lds staging ----------------
#define BM 128
#define BN 128
#define BK 32

__global__ __launch_bounds__(256, 3) void gemm_f16(const u16* __restrict__ A16,
                                                   const u16* __restrict__ BT,
                                                   int M, int K, int Ntot,
                                                   int nx, int ny,
                                                   int Nb, u16* __restrict__ Cb, int strideB,
                                                   u16* __restrict__ Cf16,
                                                   float* __restrict__ Cf32,
                                                   const float* __restrict__ biasf, int strideF) {
    __shared__ __align__(16) u16 sA[BM * BK];
    __shared__ __align__(16) u16 sB[BN * BK];
    int tid = threadIdx.x;
    int wave = tid >> 6, lane = tid & 63;
    int wr = wave >> 1, wc = wave & 1;

    // XCD-aware block swizzle
    int bid = blockIdx.x;
    int G = nx * 8;
    int g = bid / G;
    int rem = ny - g * 8;
    int rb, cb;
    if (rem >= 8) {
        int r = bid - g * G;
        rb = g * 8 + (r & 7);
        cb = r >> 3;
    } else {
        int t = bid - g * G;
        rb = g * 8 + t % rem;
        cb = t / rem;
    }
    int m0 = rb * BM, n0 = cb * BN;

    int fm = lane & 15;
    int q = lane >> 4;

    int srow = lane >> 2;
    int sch = (lane & 3) * 8;
    u16* lA0 = &sA[(wave * 32) * BK];
    u16* lA1 = &sA[(wave * 32 + 16) * BK];
    u16* lB0 = &sB[(wave * 32) * BK];
    u16* lB1 = &sB[(wave * 32 + 16) * BK];
    int ar0 = min(m0 + wave * 32 + srow, M - 1);
    int ar1 = min(m0 + wave * 32 + 16 + srow, M - 1);
    int br0 = min(n0 + wave * 32 + srow, Ntot - 1);
    int br1 = min(n0 + wave * 32 + 16 + srow, Ntot - 1);

    float4v acc[4][4];
#pragma unroll
    for (int i = 0; i < 4; i++)
#pragma unroll
        for (int j = 0; j < 4; j++) acc[i][j] = (float4v){0.f, 0.f, 0.f, 0.f};

    for (int kc = 0; kc < K; kc += BK) {
        gload16(&A16[(size_t)ar0 * K + kc + sch], lA0);
        gload16(&A16[(size_t)ar1 * K + kc + sch], lA1);
        gload16(&BT[(size_t)br0 * K + kc + sch], lB0);
        gload16(&BT[(size_t)br1 * K + kc + sch], lB1);
        __syncthreads();

        half8 ah[4];
#pragma unroll
        for (int mi = 0; mi < 4; mi++)
            ah[mi] = *(const half8*)&sA[(wr * 64 + mi * 16 + fm) * BK + q * 8];
#pragma unroll
        for (int ni = 0; ni < 4; ni++) {
            half8 bh = *(const half8*)&sB[(wc * 64 + ni * 16 + fm) * BK + q * 8];
#pragma unroll
            for (int mi = 0; mi < 4; mi++)
                acc[mi][ni] = __builtin_amdgcn_mfma_f32_16x16x32_f16(ah[mi], bh, acc[mi][ni], 0, 0, 0);
        }
        __syncthreads();
    }

#pragma unroll
    for (int mi = 0; mi < 4; mi++) {
#pragma unroll
        for (int ni = 0; ni < 4; ni++) {
            int colg = n0 + wc * 64 + ni * 16 + fm;
            if (colg >= Ntot) continue;
#pragma unroll
            for (int r = 0; r < 4; r++) {
                int rowg = m0 + wr * 64 + mi * 16 + q * 4 + r;
                if (rowg >= M) continue;
                float v = acc[mi][ni][r];
                if (colg < Nb) {
                    Cb[(size_t)rowg * strideB + colg] = f2h(v);
                } else {
                    int cf = colg - Nb;
                    float vb = v + biasf[cf];
                    if (Cf32) Cf32[(size_t)rowg * strideF + cf] = vb;
                    else      Cf16[(size_t)rowg * strideF + cf] = f2h(vb);
                }
            }
        }
    }
}

// ---------------- tall-skinny final GEMM: M x 1280 @ 1280 x 121, BK=128, XOR-swizzled LDS ----------------
#define TBK 128

__global__ __launch_bounds__(256, 2) void gemm_tall(const u16* __restrict__ h2c,
                                                    const u16* __restrict__ Gc,
                                                    const u16* __restrict__ BT,
                                                    int M,
                                                    float* __restrict__ out,
                                                    const float* __restrict__ b3) {
    __shared__ __align__(16) u16 sA[128 * TBK];
    __shared__ __align__(16) u16 sB[128 * TBK];
    int tid = threadIdx.x;
    int wave = tid >> 6, lane = tid & 63;
    int wr = wave >> 1, wc = wave & 1;
    int m0 = blockIdx.x * 128;
    int fm = lane & 15, q = lane >> 4;

    int srow = lane >> 4;          // 0..3
    int dch = lane & 15;           // dest 16B-chunk within row

    float4v acc[4][4];
#pragma unroll
    for (int i = 0; i < 4; i++)
#pragma unroll
        for (int j = 0; j < 4; j++) acc[i][j] = (float4v){0.f, 0.f, 0.f, 0.f};

    for (int kc = 0; kc < KG3; kc += TBK) {
        const u16* asrc; int astride, aoff;
        if (kc < 256) { asrc = h2c; astride = 256;  aoff = kc; }
        else          { asrc = Gc;  astride = 1024; aoff = kc - 256; }
#pragma unroll
        for (int g = 0; g < 8; g++) {
            int rA = wave * 32 + g * 4 + srow;
            int sch = (dch ^ (rA & 7)) * 8;        // pre-swizzled source chunk (u16 units)
            int arow = min(m0 + rA, M - 1);
            gload16(&asrc[(size_t)arow * astride + aoff + sch], &sA[(wave * 32 + g * 4) * TBK]);
            int brow = min(rA, NCLS - 1);
            gload16(&BT[(size_t)brow * KG3 + kc + sch], &sB[(wave * 32 + g * 4) * TBK]);
        }
        __syncthreads();

#pragma unroll
        for (int kk = 0; kk < 4; kk++) {
            int cch = kk * 4 + q;                  // logical 16B-chunk for this K-slice
            half8 ah[4];
#pragma unroll
            for (int mi = 0; mi < 4; mi++) {
                int r = wr * 64 + mi * 16 + fm;
                ah[mi] = *(const half8*)&sA[r * TBK + (cch ^ (r & 7)) * 8];
            }
#pragma unroll
            for (int ni = 0; ni < 4; ni++) {
                int rn = wc * 64 + ni * 16 + fm;
                half8 bh = *(const half8*)&sB[rn * TBK + (cch ^ (rn & 7)) * 8];
#pragma unroll
                for (int mi = 0; mi < 4; mi++)
                    acc[mi][ni] = __builtin_amdgcn_mfma_f32_16x16x32_f16(ah[mi], bh, acc[mi][ni], 0, 0, 0);
            }
        }
        __syncthreads();
    }

#pragma unroll
    for (int mi = 0; mi < 4; mi++) {
#pragma unroll
        for (int ni = 0; ni < 4; ni++) {
            int colg = wc * 64 + ni * 16 + fm;
            if (colg >= NCLS) continue;
            float bb = b3[colg];
#pragma unroll
            for (int r = 0; r < 4; r++) {
                int rowg = m0 + wr * 64 + mi * 16 + q * 4 + r;
                if (rowg >= M) continue;
                out[(size_t)rowg * NCLS + colg] = acc[mi][ni][r] + bb;
            }
        }
    }
}

// ---------------- wave-per-node attention coefficients, C=64 (layers 1/2) ----------------
__global__ __launch_bounds__(256) void alpha_wave_256(const u16* __restrict__ xh,
                                                      const float* __restrict__ a_s,
                                                      const float* __restrict__ a_d,
                                                      float* __restrict__ as_o,
                                                      float* __restrict__ ad_o, int N) {
    int lane = threadIdx.x & 63;
    int n = blockIdx.x * 4 + (threadIdx.x >> 6);
    if (n >= N) return;
    int c = lane * 4;
    uint2 v = *(const uint2*)&xh[(size_t)n * HC12 + c];
    float4 s4 = *(const float4*)&a_s[c];
    float4 d4 = *(const float4*)&a_d[c];
    float x0 = h2f((u16)(v.x & 0xffff)), x1 = h2f((u16)(v.x >> 16));
    float x2 = h2f((u16)(v.y & 0xffff)), x3 = h2f((u16)(v.y >> 16));
    float ss = x0 * s4.x + x1 * s4.y + x2 * s4.z + x3 * s4.w;
    float sd = x0 * d4.x + x1 * d4.y + x2 * d4.z + x3 * d4.w;
#pragma unroll
    for (int o = 1; o < 16; o <<= 1) {
        ss += __shfl_xor(ss, o, 64);
        sd += __shfl_xor(sd, o, 64);
    }
    if ((lane & 15) == 0) {
        as_o[n * 4 + (lane >> 4)] = ss;
        ad_o[n * 4 + (lane >> 4)] = sd;
    }
}

// ---------------- layer-3 attention coefficients from compact h2 via projected vectors ----------------
__global__ __launch_bounds__(256) void alpha3_dot(const u16* __restrict__ h2c,
                                                  const float* __restrict__ ps,
                                                  const float* __restrict__ pd,
                                                  float* __restrict__ as_o,
                                                  float* __restrict__ ad_o, int N) {
    int l = threadIdx.x & 63;
    int n = blockIdx.x * 4 + (threadIdx.x >> 6);
    if (n >= N) return;
    int h = l >> 4, li = l & 15;
    int c = li * 16;
    const u16* row = h2c + (size_t)n * HC12 + c;
    uint4 v0 = *(const uint4*)&row[0];
    uint4 v1 = *(const uint4*)&row[8];
    u32 ww[8] = {v0.x, v0.y, v0.z, v0.w, v1.x, v1.y, v1.z, v1.w};
    const float* psr = ps + h * 256 + c;
    const float* pdr = pd + h * 256 + c;
    float ss = 0.f, sd = 0.f;
#pragma unroll
    for (int j = 0; j < 8; j++) {
        float lo = h2f((u16)(ww[j] & 0xffff));
        float hi = h2f((u16)(ww[j] >> 16));
        ss += lo * psr[2 * j] + hi * psr[2 * j + 1];
        sd += lo * pdr[2 * j] + hi * pdr[2 * j + 1];
    }
#pragma unroll
    for (int o = 1; o < 16; o <<= 1) {
        ss += __shfl_xor(ss, o, 64);
        sd += __shfl_xor(sd, o, 64);
    }
    if (li == 0) {
        as_o[n * 4 + h] = ss;
        ad_o[n * 4 + h] = sd;
    }
}

// ---------------- FUSED online-softmax aggregate, HC=256 (layers 1/2) ----------------
__global__ __launch_bounds__(256) void agg_fused_256(const u16* __restrict__ xh,
                                                     const int* __restrict__ rowp,
                                                     const int* __restrict__ col,
                                                     const float* __restrict__ asrc,
                                                     const float* __restrict__ adst,
                                                     const float* __restrict__ bias,
                                                     const u16* __restrict__ res16,
                                                     u16* __restrict__ out16,
                                                     int N) {
    int l = threadIdx.x & 63;
    int n = blockIdx.x * 4 + (threadIdx.x >> 6);
    if (n >= N) return;
    int r0 = rowp[n], r1 = rowp[n + 1];
    int s_slot = l >> 5, li = l & 31;
    int c = li * 8;
    int h = li >> 3;            // own head (gather role)
    int hs = l & 3;             // stats head
    int e_st = l >> 2;          // stats edge slot 0..15
    float ad = adst[n * 4 + hs];
    float m = -3.4e38f, ssum = 0.f;
    float acc[8] = {0.f, 0.f, 0.f, 0.f, 0.f, 0.f, 0.f, 0.f};
    for (int kb = r0; kb < r1; kb += 16) {
        int cn = min(16, r1 - kb);
        int cidx = col[kb + (l & 15)];
        // ---- stats phase (online softmax) ----
        int esc = __shfl(cidx, e_st, 64);
        bool ev = e_st < cn;
        float lg = ev ? lrelu(asrc[esc * 4 + hs] + ad) : -3.4e38f;
        float cm = lg;
#pragma unroll
        for (int o = 4; o < 64; o <<= 1) cm = fmaxf(cm, __shfl_xor(cm, o, 64));
        float mn = fmaxf(m, cm);
        float es = __expf(m - mn);
        float atil = ev ? __expf(lg - mn) : 0.f;
        float cs = atil;
#pragma unroll
        for (int o = 4; o < 64; o <<= 1) cs += __shfl_xor(cs, o, 64);
        ssum = ssum * es + cs;
        m = mn;
        float eso = __shfl(es, (l & 60) | h, 64);   // rescale for own head
#pragma unroll
        for (int j = 0; j < 8; j++) acc[j] *= eso;
        // ---- gather phase ----
        int npair = (cn + 1) >> 1;
#pragma unroll 4
        for (int k = 0; k < npair; k++) {
            int e = 2 * k + s_slot;
            int em = e < cn ? e : cn - 1;
            int src = __shfl(cidx, em, 64);
            float al = __shfl(atil, em * 4 + h, 64);
            if (e >= cn) al = 0.f;
            uint4 v = *(const uint4*)&xh[(size_t)src * HC12 + c];
            acc[0] += al * h2f((u16)(v.x & 0xffff));
            acc[1] += al * h2f((u16)(v.x >> 16));
            acc[2] += al * h2f((u16)(v.y & 0xffff));
            acc[3] += al * h2f((u16)(v.y >> 16));
            acc[4] += al * h2f((u16)(v.z & 0xffff));
            acc[5] += al * h2f((u16)(v.z >> 16));
            acc[6] += al * h2f((u16)(v.w & 0xffff));
            acc[7] += al * h2f((u16)(v.w >> 16));
        }
    }
    float sso = __shfl(ssum, (l & 60) | h, 64);
    float inv = 1.f / (sso + 1e-16f);
#pragma unroll
    for (int j = 0; j < 8; j++) acc[j] += __shfl_xor(acc[j], 32, 64);
    if (l < 32) {
        uint4 rv = *(const uint4*)&res16[(size_t)n * HC12 + c];
        u32 rw[4] = {rv.x, rv.y, rv.z, rv.w};
        float4 b0 = *(const float4*)&bias[c];
        float4 b1v = *(const float4*)&bias[c + 4];
        float bb[8] = {b0.x, b0.y, b0.z, b0.w, b1v.x, b1v.y, b1v.z, b1v.w};
        union { u16 u[8]; uint4 v; } p;
#pragma unroll
        for (int j = 0; j < 8; j++) {
            float rf = h2f((u16)((rw[j >> 1] >> ((j & 1) * 16)) & 0xffff));
            float vv = acc[j] * inv + bb[j] + rf;
            float ev2 = vv > 0.f ? vv : expm1f(vv);
            p.u[j] = f2h(ev2);
        }
        *(uint4*)&out16[(size_t)n * HC12 + c] = p.v;
    }
}

// ---------------- FUSED layer-3 pre-GEMM aggregate: Gc[n,h,:] = softmax-weighted sum of h2c ----------------
// Wave per node; lane owns 4 channels c4=l*4 (8 B load, row read once per wave), all 4 heads.
__global__ __launch_bounds__(256) void agg_fused_g3(const u16* __restrict__ h2c,
                                                    u16* __restrict__ Gc,
                                                    const int* __restrict__ rowp,
                                                    const int* __restrict__ col,
                                                    const float* __restrict__ asrc,
                                                    const float* __restrict__ adst,
                                                    int N) {
    int l = threadIdx.x & 63;
    int n = blockIdx.x * 4 + (threadIdx.x >> 6);
    if (n >= N) return;
    int r0 = rowp[n], r1 = rowp[n + 1];
    int c4 = l * 4;
    int hs = l & 3;             // stats head
    int e_st = l >> 2;          // stats edge slot 0..15
    float ad = adst[n * 4 + hs];
    float m = -3.4e38f, ssum = 0.f;
    float acc[4][4];
#pragma unroll
    for (int h = 0; h < 4; h++)
#pragma unroll
        for (int j = 0; j < 4; j++) acc[h][j] = 0.f;
    for (int kb = r0; kb < r1; kb += 16) {
        int cn = min(16, r1 - kb);
        int cidx = col[kb + (l & 15)];
        // ---- stats phase (online softmax) ----
        int esc = __shfl(cidx, e_st, 64);
        bool ev = e_st < cn;
        float lg = ev ? lrelu(asrc[esc * 4 + hs] + ad) : -3.4e38f;
        float cm = lg;
#pragma unroll
        for (int o = 4; o < 64; o <<= 1) cm = fmaxf(cm, __shfl_xor(cm, o, 64));
        float mn = fmaxf(m, cm);
        float es = __expf(m - mn);
        float atil = ev ? __expf(lg - mn) : 0.f;
        float cs = atil;
#pragma unroll
        for (int o = 4; o < 64; o <<= 1) cs += __shfl_xor(cs, o, 64);
        ssum = ssum * es + cs;
        m = mn;
#pragma unroll
        for (int h = 0; h < 4; h++) {
            float eso = __shfl(es, h, 64);   // lanes 0..3 hold per-head es
#pragma unroll
            for (int j = 0; j < 4; j++) acc[h][j] *= eso;
        }
        // ---- gather phase: row read once, used for all 4 heads ----
        for (int k = 0; k < cn; k++) {
            int src = __shfl(cidx, k, 64);
            float a0 = __shfl(atil, k * 4 + 0, 64);
            float a1 = __shfl(atil, k * 4 + 1, 64);
            float a2 = __shfl(atil, k * 4 + 2, 64);
            float a3 = __shfl(atil, k * 4 + 3, 64);
            uint2 v = *(const uint2*)&h2c[(size_t)src * HC12 + c4];
            float x0 = h2f((u16)(v.x & 0xffff));
            float x1 = h2f((u16)(v.x >> 16));
            float x2 = h2f((u16)(v.y & 0xffff));
            float x3 = h2f((u16)(v.y >> 16));
            acc[0][0] += a0 * x0; acc[0][1] += a0 * x1; acc[0][2] += a0 * x2; acc[0][3] += a0 * x3;
            acc[1][0] += a1 * x0; acc[1][1] += a1 * x1; acc[1][2] += a1 * x2; acc[1][3] += a1 * x3;
            acc[2][0] += a2 * x0; acc[2][1] += a2 * x1; acc[2][2] += a2 * x2; acc[2][3] += a2 * x3;
            acc[3][0] += a3 * x0; acc[3][1] += a3 * x1; acc[3][2] += a3 * x2; acc[3][3] += a3 * x3;
        }
    }
    u16* orow = Gc + (size_t)n * 1024;
#pragma unroll
    for (int h = 0; h < 4; h++) {
        float inv = 1.f / (__shfl(ssum, h, 64) + 1e-16f);
        union { u16 u[4]; uint2 v; } p;
#pragma unroll
        for (int j = 0; j < 4; j++) p.u[j] = f2h(acc[h][j] * inv);
        *(uint2*)&orow[h * 256 + c4] = p.v;
    }
}

extern "C" void kernel_launch(void* const* d_in, const int* in_sizes, int n_in,
                              void* d_out, int out_size, void* d_ws, size_t ws_size,
                              hipStream_t stream) {
    const float* x   = (const float*)d_in[0];
    const int*   ei  = (const int*)d_in[1];
    const float* W1  = (const float*)d_in[2];
    const float* a1s = (const float*)d_in[3];
    const float* a1d = (const float*)d_in[4];
    const float* b1  = (const float*)d_in[5];
    const float* l1W = (const float*)d_in[6];
    const float* l1b = (const float*)d_in[7];
    const float* W2  = (const float*)d_in[8];
    const float* a2s = (const float*)d_in[9];
    const float* a2d = (const float*)d_in[10];
    const float* b2  = (const float*)d_in[11];
    const float* W3  = (const float*)d_in[12];
    const float* a3s = (const float*)d_in[13];
    const float* a3d = (const float*)d_in[14];
    const float* b3  = (const float*)d_in[15];
    const float* l3W = (const float*)d_in[16];
    const float* l3b = (const float*)d_in[17];

    const int N = in_sizes[0] / F_IN;   // 50000
    const int E = in_sizes[1] / 2;      // 400000
    const int* srcv = ei;
    const int* dstv = ei + E;

    char* ws = (char*)d_ws;
    size_t off = 0;
    auto alloc = [&](size_t bytes) -> char* {
        char* p = ws + off;
        off += (bytes + 255) & ~(size_t)255;
        return p;
    };
    u16*   h2c   = (u16*)alloc((size_t)N * HC12 * 2 + 256);   // compact h2 gather table
    u16*   Gc    = (u16*)alloc((size_t)N * 1024 * 2 + 256);   // aggregated G, 4 heads x 256
    u16*   xh    = (u16*)alloc((size_t)N * HC12 * 2 + 256);
    u16*   x16   = (u16*)alloc((size_t)N * F_IN * 2);
    u16*   h1f   = (u16*)alloc((size_t)N * HC12 * 2);
    u16*   lin1h = (u16*)alloc((size_t)N * HC12 * 2);
    float* as_   = (float*)alloc((size_t)N * 4 * 4);
    float* ad_   = (float*)alloc((size_t)N * 4 * 4);
    int* rowp    = (int*)alloc((size_t)(N + 1) * 4);
    int* degc    = (int*)alloc((size_t)N * 4);
    int* cur     = (int*)alloc((size_t)N * 4);
    int* part    = (int*)alloc((size_t)256 * 4);
    int* col     = (int*)alloc((size_t)E * 4 + 256);
    u16* C1 = (u16*)alloc((size_t)512 * 128 * 2);
    u16* C2 = (u16*)alloc((size_t)256 * 256 * 2);
    u16* C3 = (u16*)alloc((size_t)NCLS * KG3 * 2);
    float* ps = (float*)alloc(1024 * 4);
    float* pd = (float*)alloc(1024 * 4);
    (void)ws_size; (void)n_in; (void)out_size;

    // ---- CSR build (parallel scan) ----
    hipMemsetAsync(degc, 0, (size_t)N * 4, stream);
    hipMemsetAsync(cur, 0, (size_t)N * 4, stream);
    hist_kernel<<<(E + 255) / 256, 256, 0, stream>>>(dstv, degc, E);
    int nb = (N + 1023) / 1024;
    scan_part<<<nb, 256, 0, stream>>>(degc, part, N);
    scan_mid<<<1, 64, 0, stream>>>(part, nb);
    scan_final<<<nb, 256, 0, stream>>>(degc, part, rowp, N);
    scatter_kernel<<<(E + 255) / 256, 256, 0, stream>>>(srcv, dstv, rowp, cur, col, E);

    // ---- fused setup: weight transpose + prep3 + x conversion ----
    int NF8 = N * F_IN / 8;
    setup_all_kernel<<<(288000 + NF8 + 255) / 256, 256, 0, stream>>>(W1, l1W, W2, W3, l3W,
                                                                     a3s, a3d, x,
                                                                     C1, C2, C3, ps, pd,
                                                                     x16, NF8);

    int ny = (N + BM - 1) / BM;
    int wgrid = (N + 3) / 4;

    // ---- layer 1: one GEMM, N=512 (cols 0-255 -> xh f16, 256-511 -> lin1h f16 + l1b) ----
    gemm_f16<<<4 * ny, 256, 0, stream>>>(x16, C1, N, F_IN, 512, 4, ny,
                                         256, xh, 256, lin1h, nullptr, l1b, 256);
    alpha_wave_256<<<wgrid, 256, 0, stream>>>(xh, a1s, a1d, as_, ad_, N);
    agg_fused_256<<<wgrid, 256, 0, stream>>>(xh, rowp, col, as_, ad_, b1, lin1h, h1f, N);

    // ---- layer 2: N=256, residual = h1f; h2 written compact to h2c ----
    gemm_f16<<<2 * ny, 256, 0, stream>>>(h1f, C2, N, HC12, 256, 2, ny,
                                         256, xh, 256, nullptr, nullptr, nullptr, 0);
    alpha_wave_256<<<wgrid, 256, 0, stream>>>(xh, a2s, a2d, as_, ad_, N);
    agg_fused_256<<<wgrid, 256, 0, stream>>>(xh, rowp, col, as_, ad_, b2, h1f, h2c, N);

    // ---- layer 3: alphas from projected vectors; aggregate h2c; tall GEMM ----
    alpha3_dot<<<wgrid, 256, 0, stream>>>(h2c, ps, pd, as_, ad_, N);
    agg_fused_g3<<<wgrid, 256, 0, stream>>>(h2c, Gc, rowp, col, as_, ad_, N);
    gemm_tall<<<ny, 256, 0, stream>>>(h2c, Gc, C3, N, (float*)d_out, b3);
}